// Round 2
// baseline (1331.031 us; speedup 1.0000x reference)
//
#include <hip/hip_runtime.h>
#include <hip/hip_bf16.h>

// MambaBlock: B=2, L=1024, dim=1024, d_inner=2048, DT_RANK=64, D_STATE=16
// All inputs float32 (per reference), output float32. Internal fp32.
//
// ws layout (floats):
//   xn    : 2048*1024          = 2,097,152
//   xz    : 2048*4096          = 8,388,608   (xs = cols [0,2048), z = cols [2048,4096))
//   u     : 2048*2048          = 4,194,304
//   xdbl  : 2048*96            =   196,608   (dt_r [0,64), B [64,80), C [80,96))
//   dt    : 2048*2048          = 4,194,304
//   y     : 2048*2048          = 4,194,304
// total 23,265,280 floats = ~88.8 MiB

static __device__ __forceinline__ float siluf(float x) { return x / (1.f + __expf(-x)); }

// ---------------- LayerNorm: one block per row (m = b*L + l), dim=1024 ----------------
__global__ __launch_bounds__(256) void ln_kernel(
    const float* __restrict__ x,
    const float* __restrict__ w,
    const float* __restrict__ bias,
    float* __restrict__ xn)
{
    int m = blockIdx.x, tid = threadIdx.x;
    const float4* xr = reinterpret_cast<const float4*>(x) + (size_t)m * 256;
    float4 r = xr[tid];
    float f0 = r.x, f1 = r.y, f2 = r.z, f3 = r.w;
    float s  = f0 + f1 + f2 + f3;
    float s2 = f0*f0 + f1*f1 + f2*f2 + f3*f3;
    #pragma unroll
    for (int off = 32; off > 0; off >>= 1) {
        s  += __shfl_down(s, off);
        s2 += __shfl_down(s2, off);
    }
    __shared__ float red[8];
    if ((tid & 63) == 0) { red[tid >> 6] = s; red[4 + (tid >> 6)] = s2; }
    __syncthreads();
    float st = red[0] + red[1] + red[2] + red[3];
    float qt = red[4] + red[5] + red[6] + red[7];
    float mu   = st * (1.f / 1024.f);
    float var  = qt * (1.f / 1024.f) - mu * mu;
    float rstd = rsqrtf(var + 1e-5f);
    float4 wv = reinterpret_cast<const float4*>(w)[tid];
    float4 bv = reinterpret_cast<const float4*>(bias)[tid];
    float4 o;
    o.x = (f0 - mu) * rstd * wv.x + bv.x;
    o.y = (f1 - mu) * rstd * wv.y + bv.y;
    o.z = (f2 - mu) * rstd * wv.z + bv.z;
    o.w = (f3 - mu) * rstd * wv.w + bv.w;
    reinterpret_cast<float4*>(xn + (size_t)m * 1024)[tid] = o;
}

// ---------------- Generic GEMM-NT: C[m,n] = sum_k A[m,k] * B[n,k] ----------------
// A fp32 (M,K) lda; B fp32 (N,K) ldb. 64x64 tile, BK=16, 256 threads, 4x4 microtile.
// ep: 0 = C raw; 1 = C = softplus(acc + bias[n]); 2 = C = acc + resid[m,n]
__global__ __launch_bounds__(256) void gemm_nt(
    const float* __restrict__ A, int lda,
    const float* __restrict__ Bw, int ldb,
    int N, int K,
    float* __restrict__ C, int ldc,
    const float* __restrict__ bias,
    const float* __restrict__ resid,
    int ep)
{
    __shared__ float As[16][68];   // stride 68: 16B aligned rows, 2-way bank alias (free)
    __shared__ float Bs[16][68];
    int tid = threadIdx.x;
    int tx = tid & 15, ty = tid >> 4;
    int m0 = blockIdx.y * 64, n0 = blockIdx.x * 64;
    int lrow = tid >> 2, lcg = (tid & 3) << 2;
    float acc[4][4] = {};
    const float* Aptr = A + (size_t)(m0 + lrow) * lda + lcg;
    bool bvalid = (n0 + lrow) < N;
    const float* Bptr = Bw + (size_t)(n0 + lrow) * ldb + lcg;

    for (int k0 = 0; k0 < K; k0 += 16) {
        float4 av = *reinterpret_cast<const float4*>(Aptr + k0);
        float4 bv = make_float4(0.f, 0.f, 0.f, 0.f);
        if (bvalid) bv = *reinterpret_cast<const float4*>(Bptr + k0);
        __syncthreads();
        As[lcg + 0][lrow] = av.x; As[lcg + 1][lrow] = av.y;
        As[lcg + 2][lrow] = av.z; As[lcg + 3][lrow] = av.w;
        Bs[lcg + 0][lrow] = bv.x; Bs[lcg + 1][lrow] = bv.y;
        Bs[lcg + 2][lrow] = bv.z; Bs[lcg + 3][lrow] = bv.w;
        __syncthreads();
        #pragma unroll
        for (int k = 0; k < 16; ++k) {
            const float4 a4 = *reinterpret_cast<const float4*>(&As[k][ty << 2]);
            const float4 b4 = *reinterpret_cast<const float4*>(&Bs[k][tx << 2]);
            float aa[4] = {a4.x, a4.y, a4.z, a4.w};
            float bb[4] = {b4.x, b4.y, b4.z, b4.w};
            #pragma unroll
            for (int i = 0; i < 4; ++i)
                #pragma unroll
                for (int j = 0; j < 4; ++j)
                    acc[i][j] = fmaf(aa[i], bb[j], acc[i][j]);
        }
    }

    #pragma unroll
    for (int i = 0; i < 4; ++i) {
        int row = m0 + (ty << 2) + i;
        #pragma unroll
        for (int j = 0; j < 4; ++j) {
            int col = n0 + (tx << 2) + j;
            if (col < N) {
                float v = acc[i][j];
                if (ep == 0) {
                    C[(size_t)row * ldc + col] = v;
                } else if (ep == 1) {
                    v += bias[col];
                    v = (v > 20.f) ? v : log1pf(__expf(v));
                    C[(size_t)row * ldc + col] = v;
                } else {
                    v += resid[(size_t)row * ldc + col];
                    C[(size_t)row * ldc + col] = v;
                }
            }
        }
    }
}

// ---------------- Depthwise causal conv (width 4) + SiLU ----------------
// u[m,e] = silu(conv_b[e] + sum_k conv_w[e,k] * xs[b, l-3+k, e]),  xs = xz[:, 0:2048]
__global__ __launch_bounds__(256) void conv_silu_kernel(
    const float* __restrict__ xz,
    const float* __restrict__ cw,
    const float* __restrict__ cb,
    float* __restrict__ u)
{
    int idx = blockIdx.x * 256 + threadIdx.x;   // 4,194,304 total
    int e = idx & 2047;
    int m = idx >> 11;
    int l = m & 1023;
    float acc = cb[e];
    #pragma unroll
    for (int k = 0; k < 4; ++k) {
        int ls = l - 3 + k;
        if (ls >= 0)
            acc += cw[e * 4 + k] * xz[(size_t)(m - 3 + k) * 4096 + e];
    }
    u[(size_t)m * 2048 + e] = siluf(acc);
}

// ---------------- Selective scan ----------------
// 16 lanes per channel (b,e): lane n holds state h[n]. 65536 threads.
// y[m,e] = (sum_n h*C + u*d_skip) * silu(z)
__global__ __launch_bounds__(256) void scan_kernel(
    const float* __restrict__ dt,
    const float* __restrict__ u,
    const float* __restrict__ xdbl,
    const float* __restrict__ xz,
    const float* __restrict__ a_log,
    const float* __restrict__ d_skip,
    float* __restrict__ y)
{
    int t = blockIdx.x * 256 + threadIdx.x;
    int n = t & 15;
    int c = t >> 4;          // channel in [0, 4096)
    int e = c & 2047;
    int b = c >> 11;
    float Aen = -__expf(a_log[e * 16 + n]);
    float dsk = d_skip[e];
    const float* dt_p = dt   + (size_t)b * 1024 * 2048 + e;
    const float* u_p  = u    + (size_t)b * 1024 * 2048 + e;
    const float* z_p  = xz   + (size_t)b * 1024 * 4096 + 2048 + e;
    const float* bc_p = xdbl + (size_t)b * 1024 * 96 + 64 + n;
    float* y_p        = y    + (size_t)b * 1024 * 2048 + e;
    float h = 0.f;
    #pragma unroll 8
    for (int l = 0; l < 1024; ++l) {
        float dt_v = dt_p[(size_t)l * 2048];
        float u_v  = u_p[(size_t)l * 2048];
        float Bv   = bc_p[(size_t)l * 96];
        float Cv   = bc_p[(size_t)l * 96 + 16];
        float dA = __expf(dt_v * Aen);
        h = fmaf(dA, h, dt_v * Bv * u_v);
        float p = h * Cv;
        p += __shfl_xor(p, 1, 16);
        p += __shfl_xor(p, 2, 16);
        p += __shfl_xor(p, 4, 16);
        p += __shfl_xor(p, 8, 16);
        if (n == 0) {
            float zv = z_p[(size_t)l * 4096];
            y_p[(size_t)l * 2048] = (p + u_v * dsk) * siluf(zv);
        }
    }
}

extern "C" void kernel_launch(void* const* d_in, const int* in_sizes, int n_in,
                              void* d_out, int out_size, void* d_ws, size_t ws_size,
                              hipStream_t stream) {
    const float* x       = (const float*)d_in[0];
    const float* ln_w    = (const float*)d_in[1];
    const float* ln_b    = (const float*)d_in[2];
    const float* w_in    = (const float*)d_in[3];
    const float* conv_w  = (const float*)d_in[4];
    const float* conv_b  = (const float*)d_in[5];
    const float* w_xproj = (const float*)d_in[6];
    const float* w_dt    = (const float*)d_in[7];
    const float* b_dt    = (const float*)d_in[8];
    const float* a_log   = (const float*)d_in[9];
    const float* d_skip  = (const float*)d_in[10];
    const float* w_out   = (const float*)d_in[11];
    float* out = (float*)d_out;

    float* ws   = (float*)d_ws;
    float* xn   = ws;                      // 2,097,152
    float* xz   = xn   + 2097152;          // 8,388,608
    float* u    = xz   + 8388608;          // 4,194,304
    float* xdbl = u    + 4194304;          //   196,608
    float* dt   = xdbl + 196608;           // 4,194,304
    float* y    = dt   + 4194304;          // 4,194,304

    // 1. LayerNorm
    ln_kernel<<<2048, 256, 0, stream>>>(x, ln_w, ln_b, xn);
    // 2. xz = xn @ w_in^T   (2048 x 4096 x 1024)
    gemm_nt<<<dim3(64, 32), 256, 0, stream>>>(xn, 1024, w_in, 1024, 4096, 1024,
                                              xz, 4096, nullptr, nullptr, 0);
    // 3. depthwise conv + silu -> u
    conv_silu_kernel<<<16384, 256, 0, stream>>>(xz, conv_w, conv_b, u);
    // 4. x_dbl = u @ w_xproj^T  (2048 x 96 x 2048)
    gemm_nt<<<dim3(2, 32), 256, 0, stream>>>(u, 2048, w_xproj, 2048, 96, 2048,
                                             xdbl, 96, nullptr, nullptr, 0);
    // 5. dt = softplus(dt_r @ w_dt^T + b_dt)  (2048 x 2048 x 64)
    gemm_nt<<<dim3(32, 32), 256, 0, stream>>>(xdbl, 96, w_dt, 64, 2048, 64,
                                              dt, 2048, b_dt, nullptr, 1);
    // 6. selective scan -> y
    scan_kernel<<<256, 256, 0, stream>>>(dt, u, xdbl, xz, a_log, d_skip, y);
    // 7. out = residual + y @ w_out^T  (2048 x 1024 x 2048)
    gemm_nt<<<dim3(16, 32), 256, 0, stream>>>(y, 2048, w_out, 2048, 1024, 2048,
                                              out, 1024, nullptr, x, 2);
}

// Round 3
// 749.208 us; speedup vs baseline: 1.7766x; 1.7766x over previous
//
#include <hip/hip_runtime.h>
#include <hip/hip_bf16.h>

// MambaBlock: B=2, L=1024, dim=1024, d_inner=2048, DT_RANK=64, D_STATE=16
// All inputs float32, output float32. Internal fp32.
//
// ws layout (floats):
//   xn    : 2048*1024          = 2,097,152
//   xz    : 2048*4096          = 8,388,608   (xs = cols [0,2048), z = cols [2048,4096))
//   u     : 2048*2048          = 4,194,304
//   xdbl  : 2048*96            =   196,608   (dt_r [0,64), B [64,80), C [80,96))
//   dt    : 2048*2048          = 4,194,304
//   y     : 2048*2048          = 4,194,304
//   hpart : 16*65536           = 1,048,576   (chunked scan partials, [chunk][b*e*n])
//   Aprod : 16*65536           = 1,048,576
//   hinit : 16*65536           = 1,048,576
// total 26,411,008 floats = ~100.8 MiB

#define LC 64          // chunk length
#define NCHUNK 16      // number of chunks (L / LC)

static __device__ __forceinline__ float siluf(float x) { return x / (1.f + __expf(-x)); }

// ---------------- LayerNorm: one block per row (m = b*L + l), dim=1024 ----------------
__global__ __launch_bounds__(256) void ln_kernel(
    const float* __restrict__ x,
    const float* __restrict__ w,
    const float* __restrict__ bias,
    float* __restrict__ xn)
{
    int m = blockIdx.x, tid = threadIdx.x;
    const float4* xr = reinterpret_cast<const float4*>(x) + (size_t)m * 256;
    float4 r = xr[tid];
    float f0 = r.x, f1 = r.y, f2 = r.z, f3 = r.w;
    float s  = f0 + f1 + f2 + f3;
    float s2 = f0*f0 + f1*f1 + f2*f2 + f3*f3;
    #pragma unroll
    for (int off = 32; off > 0; off >>= 1) {
        s  += __shfl_down(s, off);
        s2 += __shfl_down(s2, off);
    }
    __shared__ float red[8];
    if ((tid & 63) == 0) { red[tid >> 6] = s; red[4 + (tid >> 6)] = s2; }
    __syncthreads();
    float st = red[0] + red[1] + red[2] + red[3];
    float qt = red[4] + red[5] + red[6] + red[7];
    float mu   = st * (1.f / 1024.f);
    float var  = qt * (1.f / 1024.f) - mu * mu;
    float rstd = rsqrtf(var + 1e-5f);
    float4 wv = reinterpret_cast<const float4*>(w)[tid];
    float4 bv = reinterpret_cast<const float4*>(bias)[tid];
    float4 o;
    o.x = (f0 - mu) * rstd * wv.x + bv.x;
    o.y = (f1 - mu) * rstd * wv.y + bv.y;
    o.z = (f2 - mu) * rstd * wv.z + bv.z;
    o.w = (f3 - mu) * rstd * wv.w + bv.w;
    reinterpret_cast<float4*>(xn + (size_t)m * 1024)[tid] = o;
}

// ---------------- Generic GEMM-NT: C[m,n] = sum_k A[m,k] * B[n,k] ----------------
__global__ __launch_bounds__(256) void gemm_nt(
    const float* __restrict__ A, int lda,
    const float* __restrict__ Bw, int ldb,
    int N, int K,
    float* __restrict__ C, int ldc,
    const float* __restrict__ bias,
    const float* __restrict__ resid,
    int ep)
{
    __shared__ float As[16][68];
    __shared__ float Bs[16][68];
    int tid = threadIdx.x;
    int tx = tid & 15, ty = tid >> 4;
    int m0 = blockIdx.y * 64, n0 = blockIdx.x * 64;
    int lrow = tid >> 2, lcg = (tid & 3) << 2;
    float acc[4][4] = {};
    const float* Aptr = A + (size_t)(m0 + lrow) * lda + lcg;
    bool bvalid = (n0 + lrow) < N;
    const float* Bptr = Bw + (size_t)(n0 + lrow) * ldb + lcg;

    for (int k0 = 0; k0 < K; k0 += 16) {
        float4 av = *reinterpret_cast<const float4*>(Aptr + k0);
        float4 bv = make_float4(0.f, 0.f, 0.f, 0.f);
        if (bvalid) bv = *reinterpret_cast<const float4*>(Bptr + k0);
        __syncthreads();
        As[lcg + 0][lrow] = av.x; As[lcg + 1][lrow] = av.y;
        As[lcg + 2][lrow] = av.z; As[lcg + 3][lrow] = av.w;
        Bs[lcg + 0][lrow] = bv.x; Bs[lcg + 1][lrow] = bv.y;
        Bs[lcg + 2][lrow] = bv.z; Bs[lcg + 3][lrow] = bv.w;
        __syncthreads();
        #pragma unroll
        for (int k = 0; k < 16; ++k) {
            const float4 a4 = *reinterpret_cast<const float4*>(&As[k][ty << 2]);
            const float4 b4 = *reinterpret_cast<const float4*>(&Bs[k][tx << 2]);
            float aa[4] = {a4.x, a4.y, a4.z, a4.w};
            float bb[4] = {b4.x, b4.y, b4.z, b4.w};
            #pragma unroll
            for (int i = 0; i < 4; ++i)
                #pragma unroll
                for (int j = 0; j < 4; ++j)
                    acc[i][j] = fmaf(aa[i], bb[j], acc[i][j]);
        }
    }

    #pragma unroll
    for (int i = 0; i < 4; ++i) {
        int row = m0 + (ty << 2) + i;
        #pragma unroll
        for (int j = 0; j < 4; ++j) {
            int col = n0 + (tx << 2) + j;
            if (col < N) {
                float v = acc[i][j];
                if (ep == 0) {
                    C[(size_t)row * ldc + col] = v;
                } else if (ep == 1) {
                    v += bias[col];
                    v = (v > 20.f) ? v : log1pf(__expf(v));
                    C[(size_t)row * ldc + col] = v;
                } else {
                    v += resid[(size_t)row * ldc + col];
                    C[(size_t)row * ldc + col] = v;
                }
            }
        }
    }
}

// ---------------- Depthwise causal conv (width 4) + SiLU ----------------
__global__ __launch_bounds__(256) void conv_silu_kernel(
    const float* __restrict__ xz,
    const float* __restrict__ cw,
    const float* __restrict__ cb,
    float* __restrict__ u)
{
    int idx = blockIdx.x * 256 + threadIdx.x;
    int e = idx & 2047;
    int m = idx >> 11;
    int l = m & 1023;
    float acc = cb[e];
    #pragma unroll
    for (int k = 0; k < 4; ++k) {
        int ls = l - 3 + k;
        if (ls >= 0)
            acc += cw[e * 4 + k] * xz[(size_t)(m - 3 + k) * 4096 + e];
    }
    u[(size_t)m * 2048 + e] = siluf(acc);
}

// ---------------- Chunked selective scan ----------------
// Block = 16 channels x 16 states, one chunk of LC=64 steps.
// blockIdx.x = ((b*128 + et)*16 + c);  e = et*16 + (tid>>4), n = tid&15.
// Pass 1: from h=0, accumulate chunk-local partial state and decay product.
__global__ __launch_bounds__(256) void scan_part1(
    const float* __restrict__ dt,
    const float* __restrict__ u,
    const float* __restrict__ xdbl,
    const float* __restrict__ a_log,
    float* __restrict__ hpart,
    float* __restrict__ Aprod)
{
    int t = threadIdx.x;
    int n = t & 15, ch = t >> 4;
    int c  = blockIdx.x & 15;
    int eb = blockIdx.x >> 4;
    int et = eb & 127;
    int b  = eb >> 7;
    int e  = et * 16 + ch;
    float Aen = -__expf(a_log[e * 16 + n]);
    const float* dt_p = dt + ((size_t)b * 1024 + c * LC) * 2048 + e;
    const float* u_p  = u  + ((size_t)b * 1024 + c * LC) * 2048 + e;
    const float* b_p  = xdbl + ((size_t)b * 1024 + c * LC) * 96 + 64 + n;
    float h = 0.f, P = 1.f;
    #pragma unroll 8
    for (int l = 0; l < LC; ++l) {
        float dt_v = dt_p[(size_t)l * 2048];
        float u_v  = u_p[(size_t)l * 2048];
        float Bv   = b_p[(size_t)l * 96];
        float dA = __expf(dt_v * Aen);
        h = fmaf(dA, h, dt_v * Bv * u_v);
        P *= dA;
    }
    int idx = c * 65536 + (b * 2048 + e) * 16 + n;
    hpart[idx] = h;
    Aprod[idx] = P;
}

// Combine: serial fold over the 16 chunks; emits each chunk's true initial state.
__global__ __launch_bounds__(256) void scan_combine(
    const float* __restrict__ hpart,
    const float* __restrict__ Aprod,
    float* __restrict__ hinit)
{
    int t = blockIdx.x * 256 + threadIdx.x;   // 65536 = b*e*n
    float h = 0.f;
    #pragma unroll
    for (int c = 0; c < NCHUNK; ++c) {
        hinit[c * 65536 + t] = h;
        h = fmaf(Aprod[c * 65536 + t], h, hpart[c * 65536 + t]);
    }
}

// Pass 2: rerun chunk scan from true initial state; emit y.
__global__ __launch_bounds__(256) void scan_part2(
    const float* __restrict__ dt,
    const float* __restrict__ u,
    const float* __restrict__ xdbl,
    const float* __restrict__ xz,
    const float* __restrict__ a_log,
    const float* __restrict__ d_skip,
    const float* __restrict__ hinit,
    float* __restrict__ y)
{
    int t = threadIdx.x;
    int n = t & 15, ch = t >> 4;
    int c  = blockIdx.x & 15;
    int eb = blockIdx.x >> 4;
    int et = eb & 127;
    int b  = eb >> 7;
    int e  = et * 16 + ch;
    float Aen = -__expf(a_log[e * 16 + n]);
    float dsk = d_skip[e];
    const float* dt_p = dt + ((size_t)b * 1024 + c * LC) * 2048 + e;
    const float* u_p  = u  + ((size_t)b * 1024 + c * LC) * 2048 + e;
    const float* z_p  = xz + ((size_t)b * 1024 + c * LC) * 4096 + 2048 + e;
    const float* bc_p = xdbl + ((size_t)b * 1024 + c * LC) * 96 + 64 + n;
    float* y_p        = y  + ((size_t)b * 1024 + c * LC) * 2048 + e;
    float h = hinit[c * 65536 + (b * 2048 + e) * 16 + n];
    #pragma unroll 4
    for (int l = 0; l < LC; ++l) {
        float dt_v = dt_p[(size_t)l * 2048];
        float u_v  = u_p[(size_t)l * 2048];
        float Bv   = bc_p[(size_t)l * 96];
        float Cv   = bc_p[(size_t)l * 96 + 16];
        float dA = __expf(dt_v * Aen);
        h = fmaf(dA, h, dt_v * Bv * u_v);
        float p = h * Cv;
        p += __shfl_xor(p, 1, 16);
        p += __shfl_xor(p, 2, 16);
        p += __shfl_xor(p, 4, 16);
        p += __shfl_xor(p, 8, 16);
        if (n == 0) {
            float zv = z_p[(size_t)l * 4096];
            y_p[(size_t)l * 2048] = (p + u_v * dsk) * siluf(zv);
        }
    }
}

extern "C" void kernel_launch(void* const* d_in, const int* in_sizes, int n_in,
                              void* d_out, int out_size, void* d_ws, size_t ws_size,
                              hipStream_t stream) {
    const float* x       = (const float*)d_in[0];
    const float* ln_w    = (const float*)d_in[1];
    const float* ln_b    = (const float*)d_in[2];
    const float* w_in    = (const float*)d_in[3];
    const float* conv_w  = (const float*)d_in[4];
    const float* conv_b  = (const float*)d_in[5];
    const float* w_xproj = (const float*)d_in[6];
    const float* w_dt    = (const float*)d_in[7];
    const float* b_dt    = (const float*)d_in[8];
    const float* a_log   = (const float*)d_in[9];
    const float* d_skip  = (const float*)d_in[10];
    const float* w_out   = (const float*)d_in[11];
    float* out = (float*)d_out;

    float* ws    = (float*)d_ws;
    float* xn    = ws;                      // 2,097,152
    float* xz    = xn    + 2097152;         // 8,388,608
    float* u     = xz    + 8388608;         // 4,194,304
    float* xdbl  = u     + 4194304;         //   196,608
    float* dt    = xdbl  + 196608;          // 4,194,304
    float* y     = dt    + 4194304;         // 4,194,304
    float* hpart = y     + 4194304;         // 1,048,576
    float* Aprod = hpart + 1048576;         // 1,048,576
    float* hinit = Aprod + 1048576;         // 1,048,576

    // 1. LayerNorm
    ln_kernel<<<2048, 256, 0, stream>>>(x, ln_w, ln_b, xn);
    // 2. xz = xn @ w_in^T   (2048 x 4096 x 1024)
    gemm_nt<<<dim3(64, 32), 256, 0, stream>>>(xn, 1024, w_in, 1024, 4096, 1024,
                                              xz, 4096, nullptr, nullptr, 0);
    // 3. depthwise conv + silu -> u
    conv_silu_kernel<<<16384, 256, 0, stream>>>(xz, conv_w, conv_b, u);
    // 4. x_dbl = u @ w_xproj^T  (2048 x 96 x 2048)
    gemm_nt<<<dim3(2, 32), 256, 0, stream>>>(u, 2048, w_xproj, 2048, 96, 2048,
                                             xdbl, 96, nullptr, nullptr, 0);
    // 5. dt = softplus(dt_r @ w_dt^T + b_dt)  (2048 x 2048 x 64)
    gemm_nt<<<dim3(32, 32), 256, 0, stream>>>(xdbl, 96, w_dt, 64, 2048, 64,
                                              dt, 2048, b_dt, nullptr, 1);
    // 6. chunked selective scan -> y
    scan_part1<<<4096, 256, 0, stream>>>(dt, u, xdbl, a_log, hpart, Aprod);
    scan_combine<<<256, 256, 0, stream>>>(hpart, Aprod, hinit);
    scan_part2<<<4096, 256, 0, stream>>>(dt, u, xdbl, xz, a_log, d_skip, hinit, y);
    // 7. out = residual + y @ w_out^T  (2048 x 1024 x 2048)
    gemm_nt<<<dim3(16, 32), 256, 0, stream>>>(y, 2048, w_out, 2048, 1024, 2048,
                                              out, 1024, nullptr, x, 2);
}

// Round 4
// 489.755 us; speedup vs baseline: 2.7177x; 1.5298x over previous
//
#include <hip/hip_runtime.h>
#include <hip/hip_bf16.h>

// MambaBlock: B=2, L=1024, dim=1024, d_inner=2048, DT_RANK=64, D_STATE=16
// Inputs fp32, output fp32. Big GEMMs in bf16 MFMA (fp32 accumulate).
//
// ws layout (float units):
//   xn_b  (bf16 2048x1024) : off 0          size 1,048,576
//   xz    (fp32 2048x4096) : off 1,048,576  size 8,388,608
//   u     (fp32 2048x2048) : off 9,437,184  size 4,194,304
//   xdbl  (fp32 2048x96)   : off 13,631,488 size 196,608
//   dt    (fp32 2048x2048) : off 13,828,096 size 4,194,304
//   hpart (fp32 16x65536)  : off 18,022,400 size 1,048,576   } y_b aliases these
//   Aprod (fp32 16x65536)  : off 19,070,976 size 1,048,576   } after combine
//   hinit (fp32 16x65536)  : off 20,119,552 size 1,048,576
//   w_in_b (bf16 4096x1024): off 21,168,128 size 2,097,152
//   w_out_b(bf16 1024x2048): off 23,265,280 size 1,048,576
//   w_dt_b (bf16 2048x64)  : off 24,313,856 size 65,536
//   dtr_b  (bf16 2048x64)  : off 24,379,392 size 65,536
// total 24,444,928 floats (< round-3's 26,411,008)

#define LC 64
#define NCHUNK 16

typedef short bf16x8 __attribute__((ext_vector_type(8)));
typedef float f32x4  __attribute__((ext_vector_type(4)));

static __device__ __forceinline__ float siluf(float x) { return x / (1.f + __expf(-x)); }
static __device__ __forceinline__ unsigned short f2bf(float f) {
    unsigned int u = __float_as_uint(f);
    unsigned int r = (u + 0x7fffu + ((u >> 16) & 1u)) >> 16;
    return (unsigned short)r;
}

// ---------------- fp32 -> bf16 convert (n4 = count/4) ----------------
__global__ __launch_bounds__(256) void f2b_kernel(
    const float* __restrict__ in, unsigned short* __restrict__ out, int n4)
{
    int i = blockIdx.x * 256 + threadIdx.x;
    if (i < n4) {
        float4 v = reinterpret_cast<const float4*>(in)[i];
        ushort4 o = { f2bf(v.x), f2bf(v.y), f2bf(v.z), f2bf(v.w) };
        reinterpret_cast<ushort4*>(out)[i] = o;
    }
}

// ---------------- extract dt_r cols [0,64) of xdbl -> bf16 ----------------
__global__ __launch_bounds__(256) void dtr_kernel(
    const float* __restrict__ xdbl, unsigned short* __restrict__ dtr)
{
    int i = blockIdx.x * 256 + threadIdx.x;   // 32768 = 2048*16
    int m = i >> 4, r = (i & 15) << 2;
    float4 v = *reinterpret_cast<const float4*>(xdbl + (size_t)m * 96 + r);
    ushort4 o = { f2bf(v.x), f2bf(v.y), f2bf(v.z), f2bf(v.w) };
    *reinterpret_cast<ushort4*>(dtr + (size_t)m * 64 + r) = o;
}

// ---------------- LayerNorm -> bf16 ----------------
__global__ __launch_bounds__(256) void ln_kernel(
    const float* __restrict__ x,
    const float* __restrict__ w,
    const float* __restrict__ bias,
    unsigned short* __restrict__ xn)
{
    int m = blockIdx.x, tid = threadIdx.x;
    const float4* xr = reinterpret_cast<const float4*>(x) + (size_t)m * 256;
    float4 r = xr[tid];
    float f0 = r.x, f1 = r.y, f2 = r.z, f3 = r.w;
    float s  = f0 + f1 + f2 + f3;
    float s2 = f0*f0 + f1*f1 + f2*f2 + f3*f3;
    #pragma unroll
    for (int off = 32; off > 0; off >>= 1) {
        s  += __shfl_down(s, off);
        s2 += __shfl_down(s2, off);
    }
    __shared__ float red[8];
    if ((tid & 63) == 0) { red[tid >> 6] = s; red[4 + (tid >> 6)] = s2; }
    __syncthreads();
    float st = red[0] + red[1] + red[2] + red[3];
    float qt = red[4] + red[5] + red[6] + red[7];
    float mu   = st * (1.f / 1024.f);
    float var  = qt * (1.f / 1024.f) - mu * mu;
    float rstd = rsqrtf(var + 1e-5f);
    float4 wv = reinterpret_cast<const float4*>(w)[tid];
    float4 bv = reinterpret_cast<const float4*>(bias)[tid];
    ushort4 o = { f2bf((f0 - mu) * rstd * wv.x + bv.x),
                  f2bf((f1 - mu) * rstd * wv.y + bv.y),
                  f2bf((f2 - mu) * rstd * wv.z + bv.z),
                  f2bf((f3 - mu) * rstd * wv.w + bv.w) };
    reinterpret_cast<ushort4*>(xn + (size_t)m * 1024)[tid] = o;
}

// ---------------- bf16 MFMA GEMM-NT: C[m,n] = sum_k A[m,k]*B[n,k] ----------------
// 128x128 tile, BK=32, 256 threads = 4 waves (2x2 of 64x64), 4x4 MFMA tiles/wave.
// M, N multiples of 128; K multiple of 32.
// ep: 0 = C raw fp32; 1 = softplus(acc + bias[n]); 2 = acc + resid[m,n]
__global__ __launch_bounds__(256) void gemm_bf16_nt(
    const unsigned short* __restrict__ A, int lda,
    const unsigned short* __restrict__ B, int ldb,
    int K,
    float* __restrict__ C, int ldc,
    const float* __restrict__ bias,
    const float* __restrict__ resid,
    int ep)
{
    __shared__ short As[128 * 32];
    __shared__ short Bs[128 * 32];
    int tid = threadIdx.x;
    int m0 = blockIdx.y * 128, n0 = blockIdx.x * 128;
    int lane = tid & 63, wave = tid >> 6;
    int wm = (wave >> 1) * 64, wn = (wave & 1) * 64;
    int frow = lane & 15, fq = lane >> 4;

    f32x4 acc[4][4] = {};

    int srow = tid >> 2;            // 0..63
    int sc   = (tid & 3) << 3;      // 0,8,16,24
    const unsigned short* Ag = A + (size_t)(m0 + srow) * lda + sc;
    const unsigned short* Bg = B + (size_t)(n0 + srow) * ldb + sc;

    for (int k0 = 0; k0 < K; k0 += 32) {
        bf16x8 a0 = *reinterpret_cast<const bf16x8*>(Ag + k0);
        bf16x8 a1 = *reinterpret_cast<const bf16x8*>(Ag + (size_t)64 * lda + k0);
        bf16x8 b0 = *reinterpret_cast<const bf16x8*>(Bg + k0);
        bf16x8 b1 = *reinterpret_cast<const bf16x8*>(Bg + (size_t)64 * ldb + k0);
        __syncthreads();
        *reinterpret_cast<bf16x8*>(As + srow * 32 + sc)        = a0;
        *reinterpret_cast<bf16x8*>(As + (srow + 64) * 32 + sc) = a1;
        *reinterpret_cast<bf16x8*>(Bs + srow * 32 + sc)        = b0;
        *reinterpret_cast<bf16x8*>(Bs + (srow + 64) * 32 + sc) = b1;
        __syncthreads();
        bf16x8 af[4], bfr[4];
        #pragma unroll
        for (int i = 0; i < 4; ++i)
            af[i] = *reinterpret_cast<const bf16x8*>(As + (wm + i * 16 + frow) * 32 + fq * 8);
        #pragma unroll
        for (int j = 0; j < 4; ++j)
            bfr[j] = *reinterpret_cast<const bf16x8*>(Bs + (wn + j * 16 + frow) * 32 + fq * 8);
        #pragma unroll
        for (int i = 0; i < 4; ++i)
            #pragma unroll
            for (int j = 0; j < 4; ++j)
                acc[i][j] = __builtin_amdgcn_mfma_f32_16x16x32_bf16(af[i], bfr[j], acc[i][j], 0, 0, 0);
    }

    // C/D layout: col = lane&15, row = (lane>>4)*4 + reg
    int cn = lane & 15, rq = (lane >> 4) * 4;
    #pragma unroll
    for (int i = 0; i < 4; ++i) {
        #pragma unroll
        for (int j = 0; j < 4; ++j) {
            #pragma unroll
            for (int r = 0; r < 4; ++r) {
                int row = m0 + wm + i * 16 + rq + r;
                int col = n0 + wn + j * 16 + cn;
                float v = acc[i][j][r];
                if (ep == 0) {
                    C[(size_t)row * ldc + col] = v;
                } else if (ep == 1) {
                    v += bias[col];
                    v = (v > 20.f) ? v : log1pf(__expf(v));
                    C[(size_t)row * ldc + col] = v;
                } else {
                    v += resid[(size_t)row * ldc + col];
                    C[(size_t)row * ldc + col] = v;
                }
            }
        }
    }
}

// ---------------- fp32 GEMM-NT (used for x_dbl: N=96) ----------------
__global__ __launch_bounds__(256) void gemm_nt(
    const float* __restrict__ A, int lda,
    const float* __restrict__ Bw, int ldb,
    int N, int K,
    float* __restrict__ C, int ldc)
{
    __shared__ float As[16][68];
    __shared__ float Bs[16][68];
    int tid = threadIdx.x;
    int tx = tid & 15, ty = tid >> 4;
    int m0 = blockIdx.y * 64, n0 = blockIdx.x * 64;
    int lrow = tid >> 2, lcg = (tid & 3) << 2;
    float acc[4][4] = {};
    const float* Aptr = A + (size_t)(m0 + lrow) * lda + lcg;
    bool bvalid = (n0 + lrow) < N;
    const float* Bptr = Bw + (size_t)(n0 + lrow) * ldb + lcg;

    for (int k0 = 0; k0 < K; k0 += 16) {
        float4 av = *reinterpret_cast<const float4*>(Aptr + k0);
        float4 bv = make_float4(0.f, 0.f, 0.f, 0.f);
        if (bvalid) bv = *reinterpret_cast<const float4*>(Bptr + k0);
        __syncthreads();
        As[lcg + 0][lrow] = av.x; As[lcg + 1][lrow] = av.y;
        As[lcg + 2][lrow] = av.z; As[lcg + 3][lrow] = av.w;
        Bs[lcg + 0][lrow] = bv.x; Bs[lcg + 1][lrow] = bv.y;
        Bs[lcg + 2][lrow] = bv.z; Bs[lcg + 3][lrow] = bv.w;
        __syncthreads();
        #pragma unroll
        for (int k = 0; k < 16; ++k) {
            const float4 a4 = *reinterpret_cast<const float4*>(&As[k][ty << 2]);
            const float4 b4 = *reinterpret_cast<const float4*>(&Bs[k][tx << 2]);
            float aa[4] = {a4.x, a4.y, a4.z, a4.w};
            float bb[4] = {b4.x, b4.y, b4.z, b4.w};
            #pragma unroll
            for (int i = 0; i < 4; ++i)
                #pragma unroll
                for (int j = 0; j < 4; ++j)
                    acc[i][j] = fmaf(aa[i], bb[j], acc[i][j]);
        }
    }

    #pragma unroll
    for (int i = 0; i < 4; ++i) {
        int row = m0 + (ty << 2) + i;
        #pragma unroll
        for (int j = 0; j < 4; ++j) {
            int col = n0 + (tx << 2) + j;
            if (col < N)
                C[(size_t)row * ldc + col] = acc[i][j];
        }
    }
}

// ---------------- Depthwise causal conv (width 4) + SiLU ----------------
__global__ __launch_bounds__(256) void conv_silu_kernel(
    const float* __restrict__ xz,
    const float* __restrict__ cw,
    const float* __restrict__ cb,
    float* __restrict__ u)
{
    int idx = blockIdx.x * 256 + threadIdx.x;
    int e = idx & 2047;
    int m = idx >> 11;
    int l = m & 1023;
    float acc = cb[e];
    #pragma unroll
    for (int k = 0; k < 4; ++k) {
        int ls = l - 3 + k;
        if (ls >= 0)
            acc += cw[e * 4 + k] * xz[(size_t)(m - 3 + k) * 4096 + e];
    }
    u[(size_t)m * 2048 + e] = siluf(acc);
}

// ---------------- Chunked selective scan ----------------
__global__ __launch_bounds__(256) void scan_part1(
    const float* __restrict__ dt,
    const float* __restrict__ u,
    const float* __restrict__ xdbl,
    const float* __restrict__ a_log,
    float* __restrict__ hpart,
    float* __restrict__ Aprod)
{
    int t = threadIdx.x;
    int n = t & 15, ch = t >> 4;
    int c  = blockIdx.x & 15;
    int eb = blockIdx.x >> 4;
    int et = eb & 127;
    int b  = eb >> 7;
    int e  = et * 16 + ch;
    float Aen = -__expf(a_log[e * 16 + n]);
    const float* dt_p = dt + ((size_t)b * 1024 + c * LC) * 2048 + e;
    const float* u_p  = u  + ((size_t)b * 1024 + c * LC) * 2048 + e;
    const float* b_p  = xdbl + ((size_t)b * 1024 + c * LC) * 96 + 64 + n;
    float h = 0.f, P = 1.f;
    #pragma unroll 8
    for (int l = 0; l < LC; ++l) {
        float dt_v = dt_p[(size_t)l * 2048];
        float u_v  = u_p[(size_t)l * 2048];
        float Bv   = b_p[(size_t)l * 96];
        float dA = __expf(dt_v * Aen);
        h = fmaf(dA, h, dt_v * Bv * u_v);
        P *= dA;
    }
    int idx = c * 65536 + (b * 2048 + e) * 16 + n;
    hpart[idx] = h;
    Aprod[idx] = P;
}

__global__ __launch_bounds__(256) void scan_combine(
    const float* __restrict__ hpart,
    const float* __restrict__ Aprod,
    float* __restrict__ hinit)
{
    int t = blockIdx.x * 256 + threadIdx.x;
    float h = 0.f;
    #pragma unroll
    for (int c = 0; c < NCHUNK; ++c) {
        hinit[c * 65536 + t] = h;
        h = fmaf(Aprod[c * 65536 + t], h, hpart[c * 65536 + t]);
    }
}

// Pass 2: emit y as bf16 (consumed by the MFMA out-proj GEMM)
__global__ __launch_bounds__(256) void scan_part2(
    const float* __restrict__ dt,
    const float* __restrict__ u,
    const float* __restrict__ xdbl,
    const float* __restrict__ xz,
    const float* __restrict__ a_log,
    const float* __restrict__ d_skip,
    const float* __restrict__ hinit,
    unsigned short* __restrict__ y)
{
    int t = threadIdx.x;
    int n = t & 15, ch = t >> 4;
    int c  = blockIdx.x & 15;
    int eb = blockIdx.x >> 4;
    int et = eb & 127;
    int b  = eb >> 7;
    int e  = et * 16 + ch;
    float Aen = -__expf(a_log[e * 16 + n]);
    float dsk = d_skip[e];
    const float* dt_p = dt + ((size_t)b * 1024 + c * LC) * 2048 + e;
    const float* u_p  = u  + ((size_t)b * 1024 + c * LC) * 2048 + e;
    const float* z_p  = xz + ((size_t)b * 1024 + c * LC) * 4096 + 2048 + e;
    const float* bc_p = xdbl + ((size_t)b * 1024 + c * LC) * 96 + 64 + n;
    unsigned short* y_p = y + ((size_t)b * 1024 + c * LC) * 2048 + e;
    float h = hinit[c * 65536 + (b * 2048 + e) * 16 + n];
    #pragma unroll 4
    for (int l = 0; l < LC; ++l) {
        float dt_v = dt_p[(size_t)l * 2048];
        float u_v  = u_p[(size_t)l * 2048];
        float Bv   = bc_p[(size_t)l * 96];
        float Cv   = bc_p[(size_t)l * 96 + 16];
        float dA = __expf(dt_v * Aen);
        h = fmaf(dA, h, dt_v * Bv * u_v);
        float p = h * Cv;
        p += __shfl_xor(p, 1, 16);
        p += __shfl_xor(p, 2, 16);
        p += __shfl_xor(p, 4, 16);
        p += __shfl_xor(p, 8, 16);
        if (n == 0) {
            float zv = z_p[(size_t)l * 4096];
            y_p[(size_t)l * 2048] = f2bf((p + u_v * dsk) * siluf(zv));
        }
    }
}

extern "C" void kernel_launch(void* const* d_in, const int* in_sizes, int n_in,
                              void* d_out, int out_size, void* d_ws, size_t ws_size,
                              hipStream_t stream) {
    const float* x       = (const float*)d_in[0];
    const float* ln_w    = (const float*)d_in[1];
    const float* ln_b    = (const float*)d_in[2];
    const float* w_in    = (const float*)d_in[3];
    const float* conv_w  = (const float*)d_in[4];
    const float* conv_b  = (const float*)d_in[5];
    const float* w_xproj = (const float*)d_in[6];
    const float* w_dt    = (const float*)d_in[7];
    const float* b_dt    = (const float*)d_in[8];
    const float* a_log   = (const float*)d_in[9];
    const float* d_skip  = (const float*)d_in[10];
    const float* w_out   = (const float*)d_in[11];
    float* out = (float*)d_out;

    float* ws = (float*)d_ws;
    unsigned short* xn_b    = (unsigned short*)(ws);                 // 2M bf16
    float* xz    = ws + 1048576;
    float* u     = ws + 9437184;
    float* xdbl  = ws + 13631488;
    float* dt    = ws + 13828096;
    float* hpart = ws + 18022400;
    float* Aprod = ws + 19070976;
    float* hinit = ws + 20119552;
    unsigned short* y_b     = (unsigned short*)(ws + 18022400);      // aliases hpart/Aprod
    unsigned short* w_in_b  = (unsigned short*)(ws + 21168128);
    unsigned short* w_out_b = (unsigned short*)(ws + 23265280);
    unsigned short* w_dt_b  = (unsigned short*)(ws + 24313856);
    unsigned short* dtr_b   = (unsigned short*)(ws + 24379392);

    // 0. weight converts (fp32 -> bf16)
    f2b_kernel<<<4096, 256, 0, stream>>>(w_in,  w_in_b,  1048576);
    f2b_kernel<<<2048, 256, 0, stream>>>(w_out, w_out_b, 524288);
    f2b_kernel<<<128,  256, 0, stream>>>(w_dt,  w_dt_b,  32768);
    // 1. LayerNorm -> bf16
    ln_kernel<<<2048, 256, 0, stream>>>(x, ln_w, ln_b, xn_b);
    // 2. xz = xn @ w_in^T   (2048 x 4096 x 1024)  MFMA
    gemm_bf16_nt<<<dim3(32, 16), 256, 0, stream>>>(xn_b, 1024, w_in_b, 1024, 1024,
                                                   xz, 4096, nullptr, nullptr, 0);
    // 3. depthwise conv + silu -> u
    conv_silu_kernel<<<16384, 256, 0, stream>>>(xz, conv_w, conv_b, u);
    // 4. x_dbl = u @ w_xproj^T  (2048 x 96 x 2048)  fp32
    gemm_nt<<<dim3(2, 32), 256, 0, stream>>>(u, 2048, w_xproj, 2048, 96, 2048, xdbl, 96);
    // 4b. dt_r -> bf16
    dtr_kernel<<<128, 256, 0, stream>>>(xdbl, dtr_b);
    // 5. dt = softplus(dt_r @ w_dt^T + b_dt)  (2048 x 2048 x 64)  MFMA
    gemm_bf16_nt<<<dim3(16, 16), 256, 0, stream>>>(dtr_b, 64, w_dt_b, 64, 64,
                                                   dt, 2048, b_dt, nullptr, 1);
    // 6. chunked selective scan -> y (bf16)
    scan_part1<<<4096, 256, 0, stream>>>(dt, u, xdbl, a_log, hpart, Aprod);
    scan_combine<<<256, 256, 0, stream>>>(hpart, Aprod, hinit);
    scan_part2<<<4096, 256, 0, stream>>>(dt, u, xdbl, xz, a_log, d_skip, hinit, y_b);
    // 7. out = residual + y @ w_out^T  (2048 x 1024 x 2048)  MFMA
    gemm_bf16_nt<<<dim3(8, 16), 256, 0, stream>>>(y_b, 2048, w_out_b, 2048, 2048,
                                                  out, 1024, nullptr, x, 2);
}

// Round 5
// 363.672 us; speedup vs baseline: 3.6600x; 1.3467x over previous
//
#include <hip/hip_runtime.h>
#include <hip/hip_bf16.h>

// MambaBlock: B=2, L=1024, dim=1024, d_inner=2048, DT_RANK=64, D_STATE=16
// Inputs fp32, output fp32. Big GEMMs bf16 MFMA; xproj fp32 split-K.
//
// ws layout (float units):
//   xn_b  (bf16 2048x1024) : off 0          size 1,048,576
//   xz    (fp32 2048x4096) : off 1,048,576  size 8,388,608
//   u     (fp32 2048x2048) : off 9,437,184  size 4,194,304
//   xdbl  (fp32 2048x96)   : off 13,631,488 size 196,608
//   dt    (fp32 2048x2048) : off 13,828,096 size 4,194,304
//   hpart (fp32 16x65536)  : off 18,022,400 size 1,048,576  } xproj partials (16x196608)
//   Aprod (fp32 16x65536)  : off 19,070,976 size 1,048,576  } alias all three before scan;
//   hinit (fp32 16x65536)  : off 20,119,552 size 1,048,576  } y_b aliases hpart+Aprod after combine
//   w_in_b (bf16 4096x1024): off 21,168,128 size 2,097,152
//   w_out_b(bf16 1024x2048): off 23,265,280 size 1,048,576
//   w_dt_b (bf16 2048x64)  : off 24,313,856 size 65,536
//   dtr_b  (bf16 2048x64)  : off 24,379,392 size 65,536
// total 24,444,928 floats

#define LC 64
#define NCHUNK 16

typedef short bf16x8 __attribute__((ext_vector_type(8)));
typedef float f32x4  __attribute__((ext_vector_type(4)));

static __device__ __forceinline__ float siluf(float x) { return x / (1.f + __expf(-x)); }
static __device__ __forceinline__ unsigned short f2bf(float f) {
    unsigned int u = __float_as_uint(f);
    unsigned int r = (u + 0x7fffu + ((u >> 16) & 1u)) >> 16;
    return (unsigned short)r;
}

// ---------------- fp32 -> bf16 convert ----------------
__global__ __launch_bounds__(256) void f2b_kernel(
    const float* __restrict__ in, unsigned short* __restrict__ out, int n4)
{
    int i = blockIdx.x * 256 + threadIdx.x;
    if (i < n4) {
        float4 v = reinterpret_cast<const float4*>(in)[i];
        ushort4 o = { f2bf(v.x), f2bf(v.y), f2bf(v.z), f2bf(v.w) };
        reinterpret_cast<ushort4*>(out)[i] = o;
    }
}

// ---------------- extract dt_r cols [0,64) of xdbl -> bf16 ----------------
__global__ __launch_bounds__(256) void dtr_kernel(
    const float* __restrict__ xdbl, unsigned short* __restrict__ dtr)
{
    int i = blockIdx.x * 256 + threadIdx.x;   // 32768 = 2048*16
    int m = i >> 4, r = (i & 15) << 2;
    float4 v = *reinterpret_cast<const float4*>(xdbl + (size_t)m * 96 + r);
    ushort4 o = { f2bf(v.x), f2bf(v.y), f2bf(v.z), f2bf(v.w) };
    *reinterpret_cast<ushort4*>(dtr + (size_t)m * 64 + r) = o;
}

// ---------------- LayerNorm -> bf16 ----------------
__global__ __launch_bounds__(256) void ln_kernel(
    const float* __restrict__ x,
    const float* __restrict__ w,
    const float* __restrict__ bias,
    unsigned short* __restrict__ xn)
{
    int m = blockIdx.x, tid = threadIdx.x;
    const float4* xr = reinterpret_cast<const float4*>(x) + (size_t)m * 256;
    float4 r = xr[tid];
    float f0 = r.x, f1 = r.y, f2 = r.z, f3 = r.w;
    float s  = f0 + f1 + f2 + f3;
    float s2 = f0*f0 + f1*f1 + f2*f2 + f3*f3;
    #pragma unroll
    for (int off = 32; off > 0; off >>= 1) {
        s  += __shfl_down(s, off);
        s2 += __shfl_down(s2, off);
    }
    __shared__ float red[8];
    if ((tid & 63) == 0) { red[tid >> 6] = s; red[4 + (tid >> 6)] = s2; }
    __syncthreads();
    float st = red[0] + red[1] + red[2] + red[3];
    float qt = red[4] + red[5] + red[6] + red[7];
    float mu   = st * (1.f / 1024.f);
    float var  = qt * (1.f / 1024.f) - mu * mu;
    float rstd = rsqrtf(var + 1e-5f);
    float4 wv = reinterpret_cast<const float4*>(w)[tid];
    float4 bv = reinterpret_cast<const float4*>(bias)[tid];
    ushort4 o = { f2bf((f0 - mu) * rstd * wv.x + bv.x),
                  f2bf((f1 - mu) * rstd * wv.y + bv.y),
                  f2bf((f2 - mu) * rstd * wv.z + bv.z),
                  f2bf((f3 - mu) * rstd * wv.w + bv.w) };
    reinterpret_cast<ushort4*>(xn + (size_t)m * 1024)[tid] = o;
}

// ---------------- bf16 MFMA GEMM-NT: C[m,n] = sum_k A[m,k]*B[n,k] ----------------
__global__ __launch_bounds__(256) void gemm_bf16_nt(
    const unsigned short* __restrict__ A, int lda,
    const unsigned short* __restrict__ B, int ldb,
    int K,
    float* __restrict__ C, int ldc,
    const float* __restrict__ bias,
    const float* __restrict__ resid,
    int ep)
{
    __shared__ short As[128 * 32];
    __shared__ short Bs[128 * 32];
    int tid = threadIdx.x;
    int m0 = blockIdx.y * 128, n0 = blockIdx.x * 128;
    int lane = tid & 63, wave = tid >> 6;
    int wm = (wave >> 1) * 64, wn = (wave & 1) * 64;
    int frow = lane & 15, fq = lane >> 4;

    f32x4 acc[4][4] = {};

    int srow = tid >> 2;
    int sc   = (tid & 3) << 3;
    const unsigned short* Ag = A + (size_t)(m0 + srow) * lda + sc;
    const unsigned short* Bg = B + (size_t)(n0 + srow) * ldb + sc;

    for (int k0 = 0; k0 < K; k0 += 32) {
        bf16x8 a0 = *reinterpret_cast<const bf16x8*>(Ag + k0);
        bf16x8 a1 = *reinterpret_cast<const bf16x8*>(Ag + (size_t)64 * lda + k0);
        bf16x8 b0 = *reinterpret_cast<const bf16x8*>(Bg + k0);
        bf16x8 b1 = *reinterpret_cast<const bf16x8*>(Bg + (size_t)64 * ldb + k0);
        __syncthreads();
        *reinterpret_cast<bf16x8*>(As + srow * 32 + sc)        = a0;
        *reinterpret_cast<bf16x8*>(As + (srow + 64) * 32 + sc) = a1;
        *reinterpret_cast<bf16x8*>(Bs + srow * 32 + sc)        = b0;
        *reinterpret_cast<bf16x8*>(Bs + (srow + 64) * 32 + sc) = b1;
        __syncthreads();
        bf16x8 af[4], bfr[4];
        #pragma unroll
        for (int i = 0; i < 4; ++i)
            af[i] = *reinterpret_cast<const bf16x8*>(As + (wm + i * 16 + frow) * 32 + fq * 8);
        #pragma unroll
        for (int j = 0; j < 4; ++j)
            bfr[j] = *reinterpret_cast<const bf16x8*>(Bs + (wn + j * 16 + frow) * 32 + fq * 8);
        #pragma unroll
        for (int i = 0; i < 4; ++i)
            #pragma unroll
            for (int j = 0; j < 4; ++j)
                acc[i][j] = __builtin_amdgcn_mfma_f32_16x16x32_bf16(af[i], bfr[j], acc[i][j], 0, 0, 0);
    }

    int cn = lane & 15, rq = (lane >> 4) * 4;
    #pragma unroll
    for (int i = 0; i < 4; ++i) {
        #pragma unroll
        for (int j = 0; j < 4; ++j) {
            #pragma unroll
            for (int r = 0; r < 4; ++r) {
                int row = m0 + wm + i * 16 + rq + r;
                int col = n0 + wn + j * 16 + cn;
                float v = acc[i][j][r];
                if (ep == 0) {
                    C[(size_t)row * ldc + col] = v;
                } else if (ep == 1) {
                    v += bias[col];
                    v = (v > 20.f) ? v : log1pf(__expf(v));
                    C[(size_t)row * ldc + col] = v;
                } else {
                    v += resid[(size_t)row * ldc + col];
                    C[(size_t)row * ldc + col] = v;
                }
            }
        }
    }
}

// ---------------- xproj split-K fp32: part[s][m][n] = sum_{k in slice s} u[m,k]*W[n,k]
// M=2048, N=96, K=2048, S=16 (slice 128). grid (32, 16), 256 threads.
__global__ __launch_bounds__(256) void xproj_splitk(
    const float* __restrict__ A,
    const float* __restrict__ B,
    float* __restrict__ part)
{
    __shared__ float As[16][68];
    __shared__ float Bs[16][100];
    int tid = threadIdx.x;
    int m0 = blockIdx.x * 64;
    int k0 = blockIdx.y * 128;
    int tx = tid & 15;     // cols tx*6 .. +5
    int ty = tid >> 4;     // rows ty*4 .. +3
    float acc[4][6] = {};
    int arow = tid >> 2, akg = (tid & 3) << 2;
    int brow1 = (256 + tid) >> 2, bkg1 = ((256 + tid) & 3) << 2;

    for (int ks = 0; ks < 128; ks += 16) {
        float4 av = *reinterpret_cast<const float4*>(A + (size_t)(m0 + arow) * 2048 + k0 + ks + akg);
        float4 bv0 = make_float4(0.f, 0.f, 0.f, 0.f), bv1 = bv0;
        if (arow < 96)  bv0 = *reinterpret_cast<const float4*>(B + (size_t)arow * 2048 + k0 + ks + akg);
        if (brow1 < 96) bv1 = *reinterpret_cast<const float4*>(B + (size_t)brow1 * 2048 + k0 + ks + bkg1);
        __syncthreads();
        As[akg + 0][arow] = av.x; As[akg + 1][arow] = av.y;
        As[akg + 2][arow] = av.z; As[akg + 3][arow] = av.w;
        if (arow < 96) {
            Bs[akg + 0][arow] = bv0.x; Bs[akg + 1][arow] = bv0.y;
            Bs[akg + 2][arow] = bv0.z; Bs[akg + 3][arow] = bv0.w;
        }
        if (brow1 < 96) {
            Bs[bkg1 + 0][brow1] = bv1.x; Bs[bkg1 + 1][brow1] = bv1.y;
            Bs[bkg1 + 2][brow1] = bv1.z; Bs[bkg1 + 3][brow1] = bv1.w;
        }
        __syncthreads();
        #pragma unroll
        for (int k = 0; k < 16; ++k) {
            float aa[4], bb[6];
            #pragma unroll
            for (int i = 0; i < 4; ++i) aa[i] = As[k][ty * 4 + i];
            #pragma unroll
            for (int j = 0; j < 6; ++j) bb[j] = Bs[k][tx * 6 + j];
            #pragma unroll
            for (int i = 0; i < 4; ++i)
                #pragma unroll
                for (int j = 0; j < 6; ++j)
                    acc[i][j] = fmaf(aa[i], bb[j], acc[i][j]);
        }
    }
    float* p = part + (size_t)blockIdx.y * 196608;
    #pragma unroll
    for (int i = 0; i < 4; ++i)
        #pragma unroll
        for (int j = 0; j < 6; ++j)
            p[(size_t)(m0 + ty * 4 + i) * 96 + tx * 6 + j] = acc[i][j];
}

__global__ __launch_bounds__(256) void xproj_reduce(
    const float* __restrict__ part, float* __restrict__ xdbl)
{
    int i = blockIdx.x * 256 + threadIdx.x;   // 196608
    float s = 0.f;
    #pragma unroll
    for (int sd = 0; sd < 16; ++sd) s += part[(size_t)sd * 196608 + i];
    xdbl[i] = s;
}

// ---------------- Depthwise causal conv (width 4) + SiLU ----------------
__global__ __launch_bounds__(256) void conv_silu_kernel(
    const float* __restrict__ xz,
    const float* __restrict__ cw,
    const float* __restrict__ cb,
    float* __restrict__ u)
{
    int idx = blockIdx.x * 256 + threadIdx.x;
    int e = idx & 2047;
    int m = idx >> 11;
    int l = m & 1023;
    float acc = cb[e];
    #pragma unroll
    for (int k = 0; k < 4; ++k) {
        int ls = l - 3 + k;
        if (ls >= 0)
            acc += cw[e * 4 + k] * xz[(size_t)(m - 3 + k) * 4096 + e];
    }
    u[(size_t)m * 2048 + e] = siluf(acc);
}

// ---------------- Chunked selective scan: 4 states per lane ----------------
// grid 1024 = (b:2) x (et:32) x (c:16); 256 threads = 64 channels x 4 ngroups.
__global__ __launch_bounds__(256) void scan_part1(
    const float* __restrict__ dt,
    const float* __restrict__ u,
    const float* __restrict__ xdbl,
    const float* __restrict__ a_log,
    float* __restrict__ hpart,
    float* __restrict__ Aprod)
{
    int tid = threadIdx.x;
    int ch = tid >> 2, ng = tid & 3;
    int bid = blockIdx.x;
    int c = bid & 15, et = (bid >> 4) & 31, b = bid >> 9;
    int e = et * 64 + ch;
    float4 al = *reinterpret_cast<const float4*>(a_log + e * 16 + ng * 4);
    float A0 = -__expf(al.x), A1 = -__expf(al.y), A2 = -__expf(al.z), A3 = -__expf(al.w);
    size_t rbase = (size_t)b * 1024 + c * LC;
    const float* dt_p = dt + rbase * 2048 + e;
    const float* u_p  = u  + rbase * 2048 + e;
    const float* b_p  = xdbl + rbase * 96 + 64 + ng * 4;
    float h0 = 0.f, h1 = 0.f, h2 = 0.f, h3 = 0.f;
    float P0 = 1.f, P1 = 1.f, P2 = 1.f, P3 = 1.f;
    #pragma unroll 4
    for (int l = 0; l < LC; ++l) {
        float dt_v = dt_p[(size_t)l * 2048];
        float u_v  = u_p[(size_t)l * 2048];
        float4 Bv  = *reinterpret_cast<const float4*>(b_p + (size_t)l * 96);
        float du = dt_v * u_v;
        float d0 = __expf(dt_v * A0), d1 = __expf(dt_v * A1);
        float d2 = __expf(dt_v * A2), d3 = __expf(dt_v * A3);
        h0 = fmaf(d0, h0, du * Bv.x); P0 *= d0;
        h1 = fmaf(d1, h1, du * Bv.y); P1 *= d1;
        h2 = fmaf(d2, h2, du * Bv.z); P2 *= d2;
        h3 = fmaf(d3, h3, du * Bv.w); P3 *= d3;
    }
    size_t oidx = (size_t)c * 65536 + ((size_t)b * 2048 + e) * 16 + ng * 4;
    *reinterpret_cast<float4*>(hpart + oidx) = make_float4(h0, h1, h2, h3);
    *reinterpret_cast<float4*>(Aprod + oidx) = make_float4(P0, P1, P2, P3);
}

__global__ __launch_bounds__(256) void scan_combine(
    const float* __restrict__ hpart,
    const float* __restrict__ Aprod,
    float* __restrict__ hinit)
{
    int t = (blockIdx.x * 256 + threadIdx.x) * 4;   // 16384 threads x float4
    float4 h = make_float4(0.f, 0.f, 0.f, 0.f);
    #pragma unroll
    for (int c = 0; c < NCHUNK; ++c) {
        *reinterpret_cast<float4*>(hinit + (size_t)c * 65536 + t) = h;
        float4 P = *reinterpret_cast<const float4*>(Aprod + (size_t)c * 65536 + t);
        float4 hp = *reinterpret_cast<const float4*>(hpart + (size_t)c * 65536 + t);
        h.x = fmaf(P.x, h.x, hp.x);
        h.y = fmaf(P.y, h.y, hp.y);
        h.z = fmaf(P.z, h.z, hp.z);
        h.w = fmaf(P.w, h.w, hp.w);
    }
}

__global__ __launch_bounds__(256) void scan_part2(
    const float* __restrict__ dt,
    const float* __restrict__ u,
    const float* __restrict__ xdbl,
    const float* __restrict__ xz,
    const float* __restrict__ a_log,
    const float* __restrict__ d_skip,
    const float* __restrict__ hinit,
    unsigned short* __restrict__ y)
{
    int tid = threadIdx.x;
    int ch = tid >> 2, ng = tid & 3;
    int bid = blockIdx.x;
    int c = bid & 15, et = (bid >> 4) & 31, b = bid >> 9;
    int e = et * 64 + ch;
    float4 al = *reinterpret_cast<const float4*>(a_log + e * 16 + ng * 4);
    float A0 = -__expf(al.x), A1 = -__expf(al.y), A2 = -__expf(al.z), A3 = -__expf(al.w);
    float dsk = d_skip[e];
    size_t rbase = (size_t)b * 1024 + c * LC;
    const float* dt_p = dt + rbase * 2048 + e;
    const float* u_p  = u  + rbase * 2048 + e;
    const float* z_p  = xz + rbase * 4096 + 2048 + e;
    const float* bc_p = xdbl + rbase * 96 + 64 + ng * 4;
    unsigned short* y_p = y + rbase * 2048 + e;
    size_t oidx = (size_t)c * 65536 + ((size_t)b * 2048 + e) * 16 + ng * 4;
    float4 hi = *reinterpret_cast<const float4*>(hinit + oidx);
    float h0 = hi.x, h1 = hi.y, h2 = hi.z, h3 = hi.w;
    #pragma unroll 4
    for (int l = 0; l < LC; ++l) {
        float dt_v = dt_p[(size_t)l * 2048];
        float u_v  = u_p[(size_t)l * 2048];
        float4 Bv  = *reinterpret_cast<const float4*>(bc_p + (size_t)l * 96);
        float4 Cv  = *reinterpret_cast<const float4*>(bc_p + (size_t)l * 96 + 16);
        float du = dt_v * u_v;
        float d0 = __expf(dt_v * A0), d1 = __expf(dt_v * A1);
        float d2 = __expf(dt_v * A2), d3 = __expf(dt_v * A3);
        h0 = fmaf(d0, h0, du * Bv.x);
        h1 = fmaf(d1, h1, du * Bv.y);
        h2 = fmaf(d2, h2, du * Bv.z);
        h3 = fmaf(d3, h3, du * Bv.w);
        float p = h0 * Cv.x + h1 * Cv.y + h2 * Cv.z + h3 * Cv.w;
        p += __shfl_xor(p, 1);
        p += __shfl_xor(p, 2);
        if (ng == 0) {
            float zv = z_p[(size_t)l * 4096];
            y_p[(size_t)l * 2048] = f2bf((p + u_v * dsk) * siluf(zv));
        }
    }
}

extern "C" void kernel_launch(void* const* d_in, const int* in_sizes, int n_in,
                              void* d_out, int out_size, void* d_ws, size_t ws_size,
                              hipStream_t stream) {
    const float* x       = (const float*)d_in[0];
    const float* ln_w    = (const float*)d_in[1];
    const float* ln_b    = (const float*)d_in[2];
    const float* w_in    = (const float*)d_in[3];
    const float* conv_w  = (const float*)d_in[4];
    const float* conv_b  = (const float*)d_in[5];
    const float* w_xproj = (const float*)d_in[6];
    const float* w_dt    = (const float*)d_in[7];
    const float* b_dt    = (const float*)d_in[8];
    const float* a_log   = (const float*)d_in[9];
    const float* d_skip  = (const float*)d_in[10];
    const float* w_out   = (const float*)d_in[11];
    float* out = (float*)d_out;

    float* ws = (float*)d_ws;
    unsigned short* xn_b    = (unsigned short*)(ws);
    float* xz    = ws + 1048576;
    float* u     = ws + 9437184;
    float* xdbl  = ws + 13631488;
    float* dt    = ws + 13828096;
    float* hpart = ws + 18022400;
    float* Aprod = ws + 19070976;
    float* hinit = ws + 20119552;
    float* xpart = ws + 18022400;                               // aliases hpart..hinit (pre-scan)
    unsigned short* y_b     = (unsigned short*)(ws + 18022400); // aliases hpart/Aprod (post-combine)
    unsigned short* w_in_b  = (unsigned short*)(ws + 21168128);
    unsigned short* w_out_b = (unsigned short*)(ws + 23265280);
    unsigned short* w_dt_b  = (unsigned short*)(ws + 24313856);
    unsigned short* dtr_b   = (unsigned short*)(ws + 24379392);

    // 0. weight converts (fp32 -> bf16)
    f2b_kernel<<<4096, 256, 0, stream>>>(w_in,  w_in_b,  1048576);
    f2b_kernel<<<2048, 256, 0, stream>>>(w_out, w_out_b, 524288);
    f2b_kernel<<<128,  256, 0, stream>>>(w_dt,  w_dt_b,  32768);
    // 1. LayerNorm -> bf16
    ln_kernel<<<2048, 256, 0, stream>>>(x, ln_w, ln_b, xn_b);
    // 2. xz = xn @ w_in^T   (2048 x 4096 x 1024)  MFMA
    gemm_bf16_nt<<<dim3(32, 16), 256, 0, stream>>>(xn_b, 1024, w_in_b, 1024, 1024,
                                                   xz, 4096, nullptr, nullptr, 0);
    // 3. depthwise conv + silu -> u
    conv_silu_kernel<<<16384, 256, 0, stream>>>(xz, conv_w, conv_b, u);
    // 4. x_dbl = u @ w_xproj^T  (2048 x 96 x 2048)  fp32 split-K
    xproj_splitk<<<dim3(32, 16), 256, 0, stream>>>(u, w_xproj, xpart);
    xproj_reduce<<<768, 256, 0, stream>>>(xpart, xdbl);
    // 4b. dt_r -> bf16
    dtr_kernel<<<128, 256, 0, stream>>>(xdbl, dtr_b);
    // 5. dt = softplus(dt_r @ w_dt^T + b_dt)  (2048 x 2048 x 64)  MFMA
    gemm_bf16_nt<<<dim3(16, 16), 256, 0, stream>>>(dtr_b, 64, w_dt_b, 64, 64,
                                                   dt, 2048, b_dt, nullptr, 1);
    // 6. chunked selective scan -> y (bf16)
    scan_part1<<<1024, 256, 0, stream>>>(dt, u, xdbl, a_log, hpart, Aprod);
    scan_combine<<<64, 256, 0, stream>>>(hpart, Aprod, hinit);
    scan_part2<<<1024, 256, 0, stream>>>(dt, u, xdbl, xz, a_log, d_skip, hinit, y_b);
    // 7. out = residual + y @ w_out^T  (2048 x 1024 x 2048)  MFMA
    gemm_bf16_nt<<<dim3(8, 16), 256, 0, stream>>>(y_b, 2048, w_out_b, 2048, 2048,
                                                  out, 1024, nullptr, x, 2);
}

// Round 6
// 338.043 us; speedup vs baseline: 3.9375x; 1.0758x over previous
//
#include <hip/hip_runtime.h>
#include <hip/hip_bf16.h>

// MambaBlock: B=2, L=1024, dim=1024, d_inner=2048, DT_RANK=64, D_STATE=16
// Inputs fp32, output fp32. Big GEMMs bf16 MFMA; xproj fp32 split-K;
// out-projection bf16 MFMA split-K x4 (partials alias dead xz region).
//
// ws layout (float units):
//   xn_b  (bf16 2048x1024) : off 0          size 1,048,576
//   xz    (fp32 2048x4096) : off 1,048,576  size 8,388,608   } out-proj partials (4 x 2,097,152)
//   u     (fp32 2048x2048) : off 9,437,184  size 4,194,304   }   alias xz after scan_part2
//   xdbl  (fp32 2048x96)   : off 13,631,488 size 196,608
//   dt    (fp32 2048x2048) : off 13,828,096 size 4,194,304
//   hpart (fp32 16x65536)  : off 18,022,400 size 1,048,576  } xproj partials (16x196608)
//   Aprod (fp32 16x65536)  : off 19,070,976 size 1,048,576  } alias all three before scan;
//   hinit (fp32 16x65536)  : off 20,119,552 size 1,048,576  } y_b aliases hpart+Aprod after combine
//   w_in_b (bf16 4096x1024): off 21,168,128 size 2,097,152
//   w_out_b(bf16 1024x2048): off 23,265,280 size 1,048,576
//   w_dt_b (bf16 2048x64)  : off 24,313,856 size 65,536
//   dtr_b  (bf16 2048x64)  : off 24,379,392 size 65,536
// total 24,444,928 floats

#define LC 64
#define NCHUNK 16

typedef short bf16x8 __attribute__((ext_vector_type(8)));
typedef float f32x4  __attribute__((ext_vector_type(4)));

static __device__ __forceinline__ float siluf(float x) { return x / (1.f + __expf(-x)); }
static __device__ __forceinline__ unsigned short f2bf(float f) {
    unsigned int u = __float_as_uint(f);
    unsigned int r = (u + 0x7fffu + ((u >> 16) & 1u)) >> 16;
    return (unsigned short)r;
}

// ---------------- fp32 -> bf16 convert ----------------
__global__ __launch_bounds__(256) void f2b_kernel(
    const float* __restrict__ in, unsigned short* __restrict__ out, int n4)
{
    int i = blockIdx.x * 256 + threadIdx.x;
    if (i < n4) {
        float4 v = reinterpret_cast<const float4*>(in)[i];
        ushort4 o = { f2bf(v.x), f2bf(v.y), f2bf(v.z), f2bf(v.w) };
        reinterpret_cast<ushort4*>(out)[i] = o;
    }
}

// ---------------- extract dt_r cols [0,64) of xdbl -> bf16 ----------------
__global__ __launch_bounds__(256) void dtr_kernel(
    const float* __restrict__ xdbl, unsigned short* __restrict__ dtr)
{
    int i = blockIdx.x * 256 + threadIdx.x;   // 32768 = 2048*16
    int m = i >> 4, r = (i & 15) << 2;
    float4 v = *reinterpret_cast<const float4*>(xdbl + (size_t)m * 96 + r);
    ushort4 o = { f2bf(v.x), f2bf(v.y), f2bf(v.z), f2bf(v.w) };
    *reinterpret_cast<ushort4*>(dtr + (size_t)m * 64 + r) = o;
}

// ---------------- LayerNorm -> bf16 ----------------
__global__ __launch_bounds__(256) void ln_kernel(
    const float* __restrict__ x,
    const float* __restrict__ w,
    const float* __restrict__ bias,
    unsigned short* __restrict__ xn)
{
    int m = blockIdx.x, tid = threadIdx.x;
    const float4* xr = reinterpret_cast<const float4*>(x) + (size_t)m * 256;
    float4 r = xr[tid];
    float f0 = r.x, f1 = r.y, f2 = r.z, f3 = r.w;
    float s  = f0 + f1 + f2 + f3;
    float s2 = f0*f0 + f1*f1 + f2*f2 + f3*f3;
    #pragma unroll
    for (int off = 32; off > 0; off >>= 1) {
        s  += __shfl_down(s, off);
        s2 += __shfl_down(s2, off);
    }
    __shared__ float red[8];
    if ((tid & 63) == 0) { red[tid >> 6] = s; red[4 + (tid >> 6)] = s2; }
    __syncthreads();
    float st = red[0] + red[1] + red[2] + red[3];
    float qt = red[4] + red[5] + red[6] + red[7];
    float mu   = st * (1.f / 1024.f);
    float var  = qt * (1.f / 1024.f) - mu * mu;
    float rstd = rsqrtf(var + 1e-5f);
    float4 wv = reinterpret_cast<const float4*>(w)[tid];
    float4 bv = reinterpret_cast<const float4*>(bias)[tid];
    ushort4 o = { f2bf((f0 - mu) * rstd * wv.x + bv.x),
                  f2bf((f1 - mu) * rstd * wv.y + bv.y),
                  f2bf((f2 - mu) * rstd * wv.z + bv.z),
                  f2bf((f3 - mu) * rstd * wv.w + bv.w) };
    reinterpret_cast<ushort4*>(xn + (size_t)m * 1024)[tid] = o;
}

// ---------------- bf16 MFMA GEMM-NT: C[m,n] = sum_k A[m,k]*B[n,k] ----------------
// 128x128 tile, BK=32, 256 threads = 4 waves (2x2 of 64x64), 4x4 MFMA tiles/wave.
// Split-K via gridDim.z: each z computes Kslice and writes C + z*Cstride.
// ep: 0 = raw fp32; 1 = softplus(acc + bias[n]); 2 = acc + resid[m,n]
__global__ __launch_bounds__(256) void gemm_bf16_nt(
    const unsigned short* __restrict__ A, int lda,
    const unsigned short* __restrict__ B, int ldb,
    int Kslice,
    float* __restrict__ C, int ldc,
    const float* __restrict__ bias,
    const float* __restrict__ resid,
    int ep, size_t Cstride)
{
    __shared__ short As[128 * 32];
    __shared__ short Bs[128 * 32];
    int tid = threadIdx.x;
    int z = blockIdx.z;
    A += (size_t)z * Kslice;
    B += (size_t)z * Kslice;
    C += (size_t)z * Cstride;
    int m0 = blockIdx.y * 128, n0 = blockIdx.x * 128;
    int lane = tid & 63, wave = tid >> 6;
    int wm = (wave >> 1) * 64, wn = (wave & 1) * 64;
    int frow = lane & 15, fq = lane >> 4;

    f32x4 acc[4][4] = {};

    int srow = tid >> 2;
    int sc   = (tid & 3) << 3;
    const unsigned short* Ag = A + (size_t)(m0 + srow) * lda + sc;
    const unsigned short* Bg = B + (size_t)(n0 + srow) * ldb + sc;

    for (int k0 = 0; k0 < Kslice; k0 += 32) {
        bf16x8 a0 = *reinterpret_cast<const bf16x8*>(Ag + k0);
        bf16x8 a1 = *reinterpret_cast<const bf16x8*>(Ag + (size_t)64 * lda + k0);
        bf16x8 b0 = *reinterpret_cast<const bf16x8*>(Bg + k0);
        bf16x8 b1 = *reinterpret_cast<const bf16x8*>(Bg + (size_t)64 * ldb + k0);
        __syncthreads();
        *reinterpret_cast<bf16x8*>(As + srow * 32 + sc)        = a0;
        *reinterpret_cast<bf16x8*>(As + (srow + 64) * 32 + sc) = a1;
        *reinterpret_cast<bf16x8*>(Bs + srow * 32 + sc)        = b0;
        *reinterpret_cast<bf16x8*>(Bs + (srow + 64) * 32 + sc) = b1;
        __syncthreads();
        bf16x8 af[4], bfr[4];
        #pragma unroll
        for (int i = 0; i < 4; ++i)
            af[i] = *reinterpret_cast<const bf16x8*>(As + (wm + i * 16 + frow) * 32 + fq * 8);
        #pragma unroll
        for (int j = 0; j < 4; ++j)
            bfr[j] = *reinterpret_cast<const bf16x8*>(Bs + (wn + j * 16 + frow) * 32 + fq * 8);
        #pragma unroll
        for (int i = 0; i < 4; ++i)
            #pragma unroll
            for (int j = 0; j < 4; ++j)
                acc[i][j] = __builtin_amdgcn_mfma_f32_16x16x32_bf16(af[i], bfr[j], acc[i][j], 0, 0, 0);
    }

    int cn = lane & 15, rq = (lane >> 4) * 4;
    #pragma unroll
    for (int i = 0; i < 4; ++i) {
        #pragma unroll
        for (int j = 0; j < 4; ++j) {
            #pragma unroll
            for (int r = 0; r < 4; ++r) {
                int row = m0 + wm + i * 16 + rq + r;
                int col = n0 + wn + j * 16 + cn;
                float v = acc[i][j][r];
                if (ep == 0) {
                    C[(size_t)row * ldc + col] = v;
                } else if (ep == 1) {
                    v += bias[col];
                    v = (v > 20.f) ? v : log1pf(__expf(v));
                    C[(size_t)row * ldc + col] = v;
                } else {
                    v += resid[(size_t)row * ldc + col];
                    C[(size_t)row * ldc + col] = v;
                }
            }
        }
    }
}

// ---------------- out = x + sum_z part[z]  (2048x1024 fp32, float4) ----------------
__global__ __launch_bounds__(256) void out_reduce(
    const float* __restrict__ part, const float* __restrict__ x,
    float* __restrict__ out)
{
    int i = blockIdx.x * 256 + threadIdx.x;   // 524288 float4s
    float4 s = reinterpret_cast<const float4*>(x)[i];
    #pragma unroll
    for (int z = 0; z < 4; ++z) {
        float4 p = reinterpret_cast<const float4*>(part + (size_t)z * 2097152)[i];
        s.x += p.x; s.y += p.y; s.z += p.z; s.w += p.w;
    }
    reinterpret_cast<float4*>(out)[i] = s;
}

// ---------------- xproj split-K fp32 ----------------
__global__ __launch_bounds__(256) void xproj_splitk(
    const float* __restrict__ A,
    const float* __restrict__ B,
    float* __restrict__ part)
{
    __shared__ float As[16][68];
    __shared__ float Bs[16][100];
    int tid = threadIdx.x;
    int m0 = blockIdx.x * 64;
    int k0 = blockIdx.y * 128;
    int tx = tid & 15;
    int ty = tid >> 4;
    float acc[4][6] = {};
    int arow = tid >> 2, akg = (tid & 3) << 2;
    int brow1 = (256 + tid) >> 2, bkg1 = ((256 + tid) & 3) << 2;

    for (int ks = 0; ks < 128; ks += 16) {
        float4 av = *reinterpret_cast<const float4*>(A + (size_t)(m0 + arow) * 2048 + k0 + ks + akg);
        float4 bv0 = make_float4(0.f, 0.f, 0.f, 0.f), bv1 = bv0;
        if (arow < 96)  bv0 = *reinterpret_cast<const float4*>(B + (size_t)arow * 2048 + k0 + ks + akg);
        if (brow1 < 96) bv1 = *reinterpret_cast<const float4*>(B + (size_t)brow1 * 2048 + k0 + ks + bkg1);
        __syncthreads();
        As[akg + 0][arow] = av.x; As[akg + 1][arow] = av.y;
        As[akg + 2][arow] = av.z; As[akg + 3][arow] = av.w;
        if (arow < 96) {
            Bs[akg + 0][arow] = bv0.x; Bs[akg + 1][arow] = bv0.y;
            Bs[akg + 2][arow] = bv0.z; Bs[akg + 3][arow] = bv0.w;
        }
        if (brow1 < 96) {
            Bs[bkg1 + 0][brow1] = bv1.x; Bs[bkg1 + 1][brow1] = bv1.y;
            Bs[bkg1 + 2][brow1] = bv1.z; Bs[bkg1 + 3][brow1] = bv1.w;
        }
        __syncthreads();
        #pragma unroll
        for (int k = 0; k < 16; ++k) {
            float aa[4], bb[6];
            #pragma unroll
            for (int i = 0; i < 4; ++i) aa[i] = As[k][ty * 4 + i];
            #pragma unroll
            for (int j = 0; j < 6; ++j) bb[j] = Bs[k][tx * 6 + j];
            #pragma unroll
            for (int i = 0; i < 4; ++i)
                #pragma unroll
                for (int j = 0; j < 6; ++j)
                    acc[i][j] = fmaf(aa[i], bb[j], acc[i][j]);
        }
    }
    float* p = part + (size_t)blockIdx.y * 196608;
    #pragma unroll
    for (int i = 0; i < 4; ++i)
        #pragma unroll
        for (int j = 0; j < 6; ++j)
            p[(size_t)(m0 + ty * 4 + i) * 96 + tx * 6 + j] = acc[i][j];
}

__global__ __launch_bounds__(256) void xproj_reduce(
    const float* __restrict__ part, float* __restrict__ xdbl)
{
    int i = blockIdx.x * 256 + threadIdx.x;   // 196608
    float s = 0.f;
    #pragma unroll
    for (int sd = 0; sd < 16; ++sd) s += part[(size_t)sd * 196608 + i];
    xdbl[i] = s;
}

// ---------------- Depthwise causal conv (width 4) + SiLU ----------------
__global__ __launch_bounds__(256) void conv_silu_kernel(
    const float* __restrict__ xz,
    const float* __restrict__ cw,
    const float* __restrict__ cb,
    float* __restrict__ u)
{
    int idx = blockIdx.x * 256 + threadIdx.x;
    int e = idx & 2047;
    int m = idx >> 11;
    int l = m & 1023;
    float acc = cb[e];
    #pragma unroll
    for (int k = 0; k < 4; ++k) {
        int ls = l - 3 + k;
        if (ls >= 0)
            acc += cw[e * 4 + k] * xz[(size_t)(m - 3 + k) * 4096 + e];
    }
    u[(size_t)m * 2048 + e] = siluf(acc);
}

// ---------------- Chunked selective scan: 4 states per lane ----------------
__global__ __launch_bounds__(256) void scan_part1(
    const float* __restrict__ dt,
    const float* __restrict__ u,
    const float* __restrict__ xdbl,
    const float* __restrict__ a_log,
    float* __restrict__ hpart,
    float* __restrict__ Aprod)
{
    int tid = threadIdx.x;
    int ch = tid >> 2, ng = tid & 3;
    int bid = blockIdx.x;
    int c = bid & 15, et = (bid >> 4) & 31, b = bid >> 9;
    int e = et * 64 + ch;
    float4 al = *reinterpret_cast<const float4*>(a_log + e * 16 + ng * 4);
    float A0 = -__expf(al.x), A1 = -__expf(al.y), A2 = -__expf(al.z), A3 = -__expf(al.w);
    size_t rbase = (size_t)b * 1024 + c * LC;
    const float* dt_p = dt + rbase * 2048 + e;
    const float* u_p  = u  + rbase * 2048 + e;
    const float* b_p  = xdbl + rbase * 96 + 64 + ng * 4;
    float h0 = 0.f, h1 = 0.f, h2 = 0.f, h3 = 0.f;
    float P0 = 1.f, P1 = 1.f, P2 = 1.f, P3 = 1.f;
    #pragma unroll 4
    for (int l = 0; l < LC; ++l) {
        float dt_v = dt_p[(size_t)l * 2048];
        float u_v  = u_p[(size_t)l * 2048];
        float4 Bv  = *reinterpret_cast<const float4*>(b_p + (size_t)l * 96);
        float du = dt_v * u_v;
        float d0 = __expf(dt_v * A0), d1 = __expf(dt_v * A1);
        float d2 = __expf(dt_v * A2), d3 = __expf(dt_v * A3);
        h0 = fmaf(d0, h0, du * Bv.x); P0 *= d0;
        h1 = fmaf(d1, h1, du * Bv.y); P1 *= d1;
        h2 = fmaf(d2, h2, du * Bv.z); P2 *= d2;
        h3 = fmaf(d3, h3, du * Bv.w); P3 *= d3;
    }
    size_t oidx = (size_t)c * 65536 + ((size_t)b * 2048 + e) * 16 + ng * 4;
    *reinterpret_cast<float4*>(hpart + oidx) = make_float4(h0, h1, h2, h3);
    *reinterpret_cast<float4*>(Aprod + oidx) = make_float4(P0, P1, P2, P3);
}

__global__ __launch_bounds__(256) void scan_combine(
    const float* __restrict__ hpart,
    const float* __restrict__ Aprod,
    float* __restrict__ hinit)
{
    int t = (blockIdx.x * 256 + threadIdx.x) * 4;
    float4 h = make_float4(0.f, 0.f, 0.f, 0.f);
    #pragma unroll
    for (int c = 0; c < NCHUNK; ++c) {
        *reinterpret_cast<float4*>(hinit + (size_t)c * 65536 + t) = h;
        float4 P = *reinterpret_cast<const float4*>(Aprod + (size_t)c * 65536 + t);
        float4 hp = *reinterpret_cast<const float4*>(hpart + (size_t)c * 65536 + t);
        h.x = fmaf(P.x, h.x, hp.x);
        h.y = fmaf(P.y, h.y, hp.y);
        h.z = fmaf(P.z, h.z, hp.z);
        h.w = fmaf(P.w, h.w, hp.w);
    }
}

__global__ __launch_bounds__(256) void scan_part2(
    const float* __restrict__ dt,
    const float* __restrict__ u,
    const float* __restrict__ xdbl,
    const float* __restrict__ xz,
    const float* __restrict__ a_log,
    const float* __restrict__ d_skip,
    const float* __restrict__ hinit,
    unsigned short* __restrict__ y)
{
    int tid = threadIdx.x;
    int ch = tid >> 2, ng = tid & 3;
    int bid = blockIdx.x;
    int c = bid & 15, et = (bid >> 4) & 31, b = bid >> 9;
    int e = et * 64 + ch;
    float4 al = *reinterpret_cast<const float4*>(a_log + e * 16 + ng * 4);
    float A0 = -__expf(al.x), A1 = -__expf(al.y), A2 = -__expf(al.z), A3 = -__expf(al.w);
    float dsk = d_skip[e];
    size_t rbase = (size_t)b * 1024 + c * LC;
    const float* dt_p = dt + rbase * 2048 + e;
    const float* u_p  = u  + rbase * 2048 + e;
    const float* z_p  = xz + rbase * 4096 + 2048 + e;
    const float* bc_p = xdbl + rbase * 96 + 64 + ng * 4;
    unsigned short* y_p = y + rbase * 2048 + e;
    size_t oidx = (size_t)c * 65536 + ((size_t)b * 2048 + e) * 16 + ng * 4;
    float4 hi = *reinterpret_cast<const float4*>(hinit + oidx);
    float h0 = hi.x, h1 = hi.y, h2 = hi.z, h3 = hi.w;
    #pragma unroll 4
    for (int l = 0; l < LC; ++l) {
        float dt_v = dt_p[(size_t)l * 2048];
        float u_v  = u_p[(size_t)l * 2048];
        float4 Bv  = *reinterpret_cast<const float4*>(bc_p + (size_t)l * 96);
        float4 Cv  = *reinterpret_cast<const float4*>(bc_p + (size_t)l * 96 + 16);
        float du = dt_v * u_v;
        float d0 = __expf(dt_v * A0), d1 = __expf(dt_v * A1);
        float d2 = __expf(dt_v * A2), d3 = __expf(dt_v * A3);
        h0 = fmaf(d0, h0, du * Bv.x);
        h1 = fmaf(d1, h1, du * Bv.y);
        h2 = fmaf(d2, h2, du * Bv.z);
        h3 = fmaf(d3, h3, du * Bv.w);
        float p = h0 * Cv.x + h1 * Cv.y + h2 * Cv.z + h3 * Cv.w;
        p += __shfl_xor(p, 1);
        p += __shfl_xor(p, 2);
        if (ng == 0) {
            float zv = z_p[(size_t)l * 4096];
            y_p[(size_t)l * 2048] = f2bf((p + u_v * dsk) * siluf(zv));
        }
    }
}

extern "C" void kernel_launch(void* const* d_in, const int* in_sizes, int n_in,
                              void* d_out, int out_size, void* d_ws, size_t ws_size,
                              hipStream_t stream) {
    const float* x       = (const float*)d_in[0];
    const float* ln_w    = (const float*)d_in[1];
    const float* ln_b    = (const float*)d_in[2];
    const float* w_in    = (const float*)d_in[3];
    const float* conv_w  = (const float*)d_in[4];
    const float* conv_b  = (const float*)d_in[5];
    const float* w_xproj = (const float*)d_in[6];
    const float* w_dt    = (const float*)d_in[7];
    const float* b_dt    = (const float*)d_in[8];
    const float* a_log   = (const float*)d_in[9];
    const float* d_skip  = (const float*)d_in[10];
    const float* w_out   = (const float*)d_in[11];
    float* out = (float*)d_out;

    float* ws = (float*)d_ws;
    unsigned short* xn_b    = (unsigned short*)(ws);
    float* xz    = ws + 1048576;
    float* u     = ws + 9437184;
    float* xdbl  = ws + 13631488;
    float* dt    = ws + 13828096;
    float* hpart = ws + 18022400;
    float* Aprod = ws + 19070976;
    float* hinit = ws + 20119552;
    float* xpart = ws + 18022400;                               // aliases hpart..hinit (pre-scan)
    float* opart = xz;                                          // aliases xz (dead after scan_part2)
    unsigned short* y_b     = (unsigned short*)(ws + 18022400); // aliases hpart/Aprod (post-combine)
    unsigned short* w_in_b  = (unsigned short*)(ws + 21168128);
    unsigned short* w_out_b = (unsigned short*)(ws + 23265280);
    unsigned short* w_dt_b  = (unsigned short*)(ws + 24313856);
    unsigned short* dtr_b   = (unsigned short*)(ws + 24379392);

    // 0. weight converts (fp32 -> bf16)
    f2b_kernel<<<4096, 256, 0, stream>>>(w_in,  w_in_b,  1048576);
    f2b_kernel<<<2048, 256, 0, stream>>>(w_out, w_out_b, 524288);
    f2b_kernel<<<128,  256, 0, stream>>>(w_dt,  w_dt_b,  32768);
    // 1. LayerNorm -> bf16
    ln_kernel<<<2048, 256, 0, stream>>>(x, ln_w, ln_b, xn_b);
    // 2. xz = xn @ w_in^T   (2048 x 4096 x 1024)  MFMA
    gemm_bf16_nt<<<dim3(32, 16, 1), 256, 0, stream>>>(xn_b, 1024, w_in_b, 1024, 1024,
                                                      xz, 4096, nullptr, nullptr, 0, 0);
    // 3. depthwise conv + silu -> u
    conv_silu_kernel<<<16384, 256, 0, stream>>>(xz, conv_w, conv_b, u);
    // 4. x_dbl = u @ w_xproj^T  (2048 x 96 x 2048)  fp32 split-K
    xproj_splitk<<<dim3(32, 16), 256, 0, stream>>>(u, w_xproj, xpart);
    xproj_reduce<<<768, 256, 0, stream>>>(xpart, xdbl);
    // 4b. dt_r -> bf16
    dtr_kernel<<<128, 256, 0, stream>>>(xdbl, dtr_b);
    // 5. dt = softplus(dt_r @ w_dt^T + b_dt)  (2048 x 2048 x 64)  MFMA
    gemm_bf16_nt<<<dim3(16, 16, 1), 256, 0, stream>>>(dtr_b, 64, w_dt_b, 64, 64,
                                                      dt, 2048, b_dt, nullptr, 1, 0);
    // 6. chunked selective scan -> y (bf16)
    scan_part1<<<1024, 256, 0, stream>>>(dt, u, xdbl, a_log, hpart, Aprod);
    scan_combine<<<64, 256, 0, stream>>>(hpart, Aprod, hinit);
    scan_part2<<<1024, 256, 0, stream>>>(dt, u, xdbl, xz, a_log, d_skip, hinit, y_b);
    // 7. out-proj split-K x4: partials then reduce(+residual)
    gemm_bf16_nt<<<dim3(8, 16, 4), 256, 0, stream>>>(y_b, 2048, w_out_b, 2048, 512,
                                                     opart, 1024, nullptr, nullptr, 0, 2097152);
    out_reduce<<<2048, 256, 0, stream>>>(opart, x, out);
}

// Round 7
// 317.854 us; speedup vs baseline: 4.1876x; 1.0635x over previous
//
#include <hip/hip_runtime.h>
#include <hip/hip_bf16.h>

// MambaBlock: B=2, L=1024, dim=1024, d_inner=2048, DT_RANK=64, D_STATE=16
// Inputs fp32, output fp32. Big GEMMs bf16 MFMA; xproj fp32 split-K;
// out-projection bf16 MFMA split-K x4. Scan: LC=32, NCHUNK=32 (32 waves/CU).
//
// ws layout (float units), with time-multiplexed aliases:
//   xn_b  (bf16 2048x1024) : off 0          size 1,048,576   dead after gemm2
//   xz    (fp32 2048x4096) : off 1,048,576  size 8,388,608   z-half live till part2;
//                                                            out-proj partials alias after
//   u     (fp32 2048x2048) : off 9,437,184  size 4,194,304
//   xdbl  (fp32 2048x96)   : off 13,631,488 size 196,608
//   dt    (fp32 2048x2048) : off 13,828,096 size 4,194,304
//   scan scratch (6M):       off 18,022,400 .. 24,313,856:
//     hpart (32x65536) @ 18,022,400   Aprod (32x65536) @ 20,119,552
//     hinit (32x65536) @ 22,216,704   (Aprod/hinit spill into dead w_in_b)
//     y_b (bf16 2048x2048 = 2M fu) @ 18,022,400 after combine (hpart/Aprod dead)
//   xpart (16x196608)      : off 18,022,400 (pre-scan alias, xproj partials)
//   w_in_b (bf16)          : off 21,168,128 size 2,097,152   dead after gemm2
//   w_out_b(bf16)          : off 23,265,280 size 1,048,576   converted AFTER part2
//   w_dt_b (bf16 2048x64)  : off 24,313,856 size 65,536
//   dtr_b  (bf16 2048x64)  : off 24,379,392 size 65,536
// total 24,444,928 floats

#define LC 32
#define NCHUNK 32

typedef short bf16x8 __attribute__((ext_vector_type(8)));
typedef float f32x4  __attribute__((ext_vector_type(4)));

static __device__ __forceinline__ float siluf(float x) { return x / (1.f + __expf(-x)); }
static __device__ __forceinline__ unsigned short f2bf(float f) {
    unsigned int u = __float_as_uint(f);
    unsigned int r = (u + 0x7fffu + ((u >> 16) & 1u)) >> 16;
    return (unsigned short)r;
}

// ---------------- fp32 -> bf16 convert ----------------
__global__ __launch_bounds__(256) void f2b_kernel(
    const float* __restrict__ in, unsigned short* __restrict__ out, int n4)
{
    int i = blockIdx.x * 256 + threadIdx.x;
    if (i < n4) {
        float4 v = reinterpret_cast<const float4*>(in)[i];
        ushort4 o = { f2bf(v.x), f2bf(v.y), f2bf(v.z), f2bf(v.w) };
        reinterpret_cast<ushort4*>(out)[i] = o;
    }
}

// ---------------- extract dt_r cols [0,64) of xdbl -> bf16 ----------------
__global__ __launch_bounds__(256) void dtr_kernel(
    const float* __restrict__ xdbl, unsigned short* __restrict__ dtr)
{
    int i = blockIdx.x * 256 + threadIdx.x;   // 32768 = 2048*16
    int m = i >> 4, r = (i & 15) << 2;
    float4 v = *reinterpret_cast<const float4*>(xdbl + (size_t)m * 96 + r);
    ushort4 o = { f2bf(v.x), f2bf(v.y), f2bf(v.z), f2bf(v.w) };
    *reinterpret_cast<ushort4*>(dtr + (size_t)m * 64 + r) = o;
}

// ---------------- LayerNorm -> bf16 ----------------
__global__ __launch_bounds__(256) void ln_kernel(
    const float* __restrict__ x,
    const float* __restrict__ w,
    const float* __restrict__ bias,
    unsigned short* __restrict__ xn)
{
    int m = blockIdx.x, tid = threadIdx.x;
    const float4* xr = reinterpret_cast<const float4*>(x) + (size_t)m * 256;
    float4 r = xr[tid];
    float f0 = r.x, f1 = r.y, f2 = r.z, f3 = r.w;
    float s  = f0 + f1 + f2 + f3;
    float s2 = f0*f0 + f1*f1 + f2*f2 + f3*f3;
    #pragma unroll
    for (int off = 32; off > 0; off >>= 1) {
        s  += __shfl_down(s, off);
        s2 += __shfl_down(s2, off);
    }
    __shared__ float red[8];
    if ((tid & 63) == 0) { red[tid >> 6] = s; red[4 + (tid >> 6)] = s2; }
    __syncthreads();
    float st = red[0] + red[1] + red[2] + red[3];
    float qt = red[4] + red[5] + red[6] + red[7];
    float mu   = st * (1.f / 1024.f);
    float var  = qt * (1.f / 1024.f) - mu * mu;
    float rstd = rsqrtf(var + 1e-5f);
    float4 wv = reinterpret_cast<const float4*>(w)[tid];
    float4 bv = reinterpret_cast<const float4*>(bias)[tid];
    ushort4 o = { f2bf((f0 - mu) * rstd * wv.x + bv.x),
                  f2bf((f1 - mu) * rstd * wv.y + bv.y),
                  f2bf((f2 - mu) * rstd * wv.z + bv.z),
                  f2bf((f3 - mu) * rstd * wv.w + bv.w) };
    reinterpret_cast<ushort4*>(xn + (size_t)m * 1024)[tid] = o;
}

// ---------------- bf16 MFMA GEMM-NT ----------------
__global__ __launch_bounds__(256) void gemm_bf16_nt(
    const unsigned short* __restrict__ A, int lda,
    const unsigned short* __restrict__ B, int ldb,
    int Kslice,
    float* __restrict__ C, int ldc,
    const float* __restrict__ bias,
    const float* __restrict__ resid,
    int ep, size_t Cstride)
{
    __shared__ short As[128 * 32];
    __shared__ short Bs[128 * 32];
    int tid = threadIdx.x;
    int z = blockIdx.z;
    A += (size_t)z * Kslice;
    B += (size_t)z * Kslice;
    C += (size_t)z * Cstride;
    int m0 = blockIdx.y * 128, n0 = blockIdx.x * 128;
    int lane = tid & 63, wave = tid >> 6;
    int wm = (wave >> 1) * 64, wn = (wave & 1) * 64;
    int frow = lane & 15, fq = lane >> 4;

    f32x4 acc[4][4] = {};

    int srow = tid >> 2;
    int sc   = (tid & 3) << 3;
    const unsigned short* Ag = A + (size_t)(m0 + srow) * lda + sc;
    const unsigned short* Bg = B + (size_t)(n0 + srow) * ldb + sc;

    for (int k0 = 0; k0 < Kslice; k0 += 32) {
        bf16x8 a0 = *reinterpret_cast<const bf16x8*>(Ag + k0);
        bf16x8 a1 = *reinterpret_cast<const bf16x8*>(Ag + (size_t)64 * lda + k0);
        bf16x8 b0 = *reinterpret_cast<const bf16x8*>(Bg + k0);
        bf16x8 b1 = *reinterpret_cast<const bf16x8*>(Bg + (size_t)64 * ldb + k0);
        __syncthreads();
        *reinterpret_cast<bf16x8*>(As + srow * 32 + sc)        = a0;
        *reinterpret_cast<bf16x8*>(As + (srow + 64) * 32 + sc) = a1;
        *reinterpret_cast<bf16x8*>(Bs + srow * 32 + sc)        = b0;
        *reinterpret_cast<bf16x8*>(Bs + (srow + 64) * 32 + sc) = b1;
        __syncthreads();
        bf16x8 af[4], bfr[4];
        #pragma unroll
        for (int i = 0; i < 4; ++i)
            af[i] = *reinterpret_cast<const bf16x8*>(As + (wm + i * 16 + frow) * 32 + fq * 8);
        #pragma unroll
        for (int j = 0; j < 4; ++j)
            bfr[j] = *reinterpret_cast<const bf16x8*>(Bs + (wn + j * 16 + frow) * 32 + fq * 8);
        #pragma unroll
        for (int i = 0; i < 4; ++i)
            #pragma unroll
            for (int j = 0; j < 4; ++j)
                acc[i][j] = __builtin_amdgcn_mfma_f32_16x16x32_bf16(af[i], bfr[j], acc[i][j], 0, 0, 0);
    }

    int cn = lane & 15, rq = (lane >> 4) * 4;
    #pragma unroll
    for (int i = 0; i < 4; ++i) {
        #pragma unroll
        for (int j = 0; j < 4; ++j) {
            #pragma unroll
            for (int r = 0; r < 4; ++r) {
                int row = m0 + wm + i * 16 + rq + r;
                int col = n0 + wn + j * 16 + cn;
                float v = acc[i][j][r];
                if (ep == 0) {
                    C[(size_t)row * ldc + col] = v;
                } else if (ep == 1) {
                    v += bias[col];
                    v = (v > 20.f) ? v : log1pf(__expf(v));
                    C[(size_t)row * ldc + col] = v;
                } else {
                    v += resid[(size_t)row * ldc + col];
                    C[(size_t)row * ldc + col] = v;
                }
            }
        }
    }
}

// ---------------- out = x + sum_z part[z] ----------------
__global__ __launch_bounds__(256) void out_reduce(
    const float* __restrict__ part, const float* __restrict__ x,
    float* __restrict__ out)
{
    int i = blockIdx.x * 256 + threadIdx.x;
    float4 s = reinterpret_cast<const float4*>(x)[i];
    #pragma unroll
    for (int z = 0; z < 4; ++z) {
        float4 p = reinterpret_cast<const float4*>(part + (size_t)z * 2097152)[i];
        s.x += p.x; s.y += p.y; s.z += p.z; s.w += p.w;
    }
    reinterpret_cast<float4*>(out)[i] = s;
}

// ---------------- xproj split-K fp32 ----------------
__global__ __launch_bounds__(256) void xproj_splitk(
    const float* __restrict__ A,
    const float* __restrict__ B,
    float* __restrict__ part)
{
    __shared__ float As[16][68];
    __shared__ float Bs[16][100];
    int tid = threadIdx.x;
    int m0 = blockIdx.x * 64;
    int k0 = blockIdx.y * 128;
    int tx = tid & 15;
    int ty = tid >> 4;
    float acc[4][6] = {};
    int arow = tid >> 2, akg = (tid & 3) << 2;
    int brow1 = (256 + tid) >> 2, bkg1 = ((256 + tid) & 3) << 2;

    for (int ks = 0; ks < 128; ks += 16) {
        float4 av = *reinterpret_cast<const float4*>(A + (size_t)(m0 + arow) * 2048 + k0 + ks + akg);
        float4 bv0 = make_float4(0.f, 0.f, 0.f, 0.f), bv1 = bv0;
        if (arow < 96)  bv0 = *reinterpret_cast<const float4*>(B + (size_t)arow * 2048 + k0 + ks + akg);
        if (brow1 < 96) bv1 = *reinterpret_cast<const float4*>(B + (size_t)brow1 * 2048 + k0 + ks + bkg1);
        __syncthreads();
        As[akg + 0][arow] = av.x; As[akg + 1][arow] = av.y;
        As[akg + 2][arow] = av.z; As[akg + 3][arow] = av.w;
        if (arow < 96) {
            Bs[akg + 0][arow] = bv0.x; Bs[akg + 1][arow] = bv0.y;
            Bs[akg + 2][arow] = bv0.z; Bs[akg + 3][arow] = bv0.w;
        }
        if (brow1 < 96) {
            Bs[bkg1 + 0][brow1] = bv1.x; Bs[bkg1 + 1][brow1] = bv1.y;
            Bs[bkg1 + 2][brow1] = bv1.z; Bs[bkg1 + 3][brow1] = bv1.w;
        }
        __syncthreads();
        #pragma unroll
        for (int k = 0; k < 16; ++k) {
            float aa[4], bb[6];
            #pragma unroll
            for (int i = 0; i < 4; ++i) aa[i] = As[k][ty * 4 + i];
            #pragma unroll
            for (int j = 0; j < 6; ++j) bb[j] = Bs[k][tx * 6 + j];
            #pragma unroll
            for (int i = 0; i < 4; ++i)
                #pragma unroll
                for (int j = 0; j < 6; ++j)
                    acc[i][j] = fmaf(aa[i], bb[j], acc[i][j]);
        }
    }
    float* p = part + (size_t)blockIdx.y * 196608;
    #pragma unroll
    for (int i = 0; i < 4; ++i)
        #pragma unroll
        for (int j = 0; j < 6; ++j)
            p[(size_t)(m0 + ty * 4 + i) * 96 + tx * 6 + j] = acc[i][j];
}

__global__ __launch_bounds__(256) void xproj_reduce(
    const float* __restrict__ part, float* __restrict__ xdbl)
{
    int i = blockIdx.x * 256 + threadIdx.x;
    float s = 0.f;
    #pragma unroll
    for (int sd = 0; sd < 16; ++sd) s += part[(size_t)sd * 196608 + i];
    xdbl[i] = s;
}

// ---------------- Depthwise causal conv (width 4) + SiLU ----------------
__global__ __launch_bounds__(256) void conv_silu_kernel(
    const float* __restrict__ xz,
    const float* __restrict__ cw,
    const float* __restrict__ cb,
    float* __restrict__ u)
{
    int idx = blockIdx.x * 256 + threadIdx.x;
    int e = idx & 2047;
    int m = idx >> 11;
    int l = m & 1023;
    float acc = cb[e];
    #pragma unroll
    for (int k = 0; k < 4; ++k) {
        int ls = l - 3 + k;
        if (ls >= 0)
            acc += cw[e * 4 + k] * xz[(size_t)(m - 3 + k) * 4096 + e];
    }
    u[(size_t)m * 2048 + e] = siluf(acc);
}

// ---------------- Chunked selective scan: 4 states/lane, LC=32, 32 chunks ----------------
// grid 2048 = (b:2) x (et:32) x (c:32); 256 threads = 64 channels x 4 ngroups.
__global__ __launch_bounds__(256) void scan_part1(
    const float* __restrict__ dt,
    const float* __restrict__ u,
    const float* __restrict__ xdbl,
    const float* __restrict__ a_log,
    float* __restrict__ hpart,
    float* __restrict__ Aprod)
{
    int tid = threadIdx.x;
    int ch = tid >> 2, ng = tid & 3;
    int bid = blockIdx.x;
    int c = bid & 31, et = (bid >> 5) & 31, b = bid >> 10;
    int e = et * 64 + ch;
    float4 al = *reinterpret_cast<const float4*>(a_log + e * 16 + ng * 4);
    float A0 = -__expf(al.x), A1 = -__expf(al.y), A2 = -__expf(al.z), A3 = -__expf(al.w);
    size_t rbase = (size_t)b * 1024 + c * LC;
    const float* dt_p = dt + rbase * 2048 + e;
    const float* u_p  = u  + rbase * 2048 + e;
    const float* b_p  = xdbl + rbase * 96 + 64 + ng * 4;
    float h0 = 0.f, h1 = 0.f, h2 = 0.f, h3 = 0.f;
    float P0 = 1.f, P1 = 1.f, P2 = 1.f, P3 = 1.f;
    #pragma unroll 4
    for (int l = 0; l < LC; ++l) {
        float dt_v = dt_p[(size_t)l * 2048];
        float u_v  = u_p[(size_t)l * 2048];
        float4 Bv  = *reinterpret_cast<const float4*>(b_p + (size_t)l * 96);
        float du = dt_v * u_v;
        float d0 = __expf(dt_v * A0), d1 = __expf(dt_v * A1);
        float d2 = __expf(dt_v * A2), d3 = __expf(dt_v * A3);
        h0 = fmaf(d0, h0, du * Bv.x); P0 *= d0;
        h1 = fmaf(d1, h1, du * Bv.y); P1 *= d1;
        h2 = fmaf(d2, h2, du * Bv.z); P2 *= d2;
        h3 = fmaf(d3, h3, du * Bv.w); P3 *= d3;
    }
    size_t oidx = (size_t)c * 65536 + ((size_t)b * 2048 + e) * 16 + ng * 4;
    *reinterpret_cast<float4*>(hpart + oidx) = make_float4(h0, h1, h2, h3);
    *reinterpret_cast<float4*>(Aprod + oidx) = make_float4(P0, P1, P2, P3);
}

__global__ __launch_bounds__(256) void scan_combine(
    const float* __restrict__ hpart,
    const float* __restrict__ Aprod,
    float* __restrict__ hinit)
{
    int t = (blockIdx.x * 256 + threadIdx.x) * 4;   // 16384 threads x float4
    float4 h = make_float4(0.f, 0.f, 0.f, 0.f);
    #pragma unroll
    for (int c = 0; c < NCHUNK; ++c) {
        *reinterpret_cast<float4*>(hinit + (size_t)c * 65536 + t) = h;
        float4 P = *reinterpret_cast<const float4*>(Aprod + (size_t)c * 65536 + t);
        float4 hp = *reinterpret_cast<const float4*>(hpart + (size_t)c * 65536 + t);
        h.x = fmaf(P.x, h.x, hp.x);
        h.y = fmaf(P.y, h.y, hp.y);
        h.z = fmaf(P.z, h.z, hp.z);
        h.w = fmaf(P.w, h.w, hp.w);
    }
}

__global__ __launch_bounds__(256) void scan_part2(
    const float* __restrict__ dt,
    const float* __restrict__ u,
    const float* __restrict__ xdbl,
    const float* __restrict__ xz,
    const float* __restrict__ a_log,
    const float* __restrict__ d_skip,
    const float* __restrict__ hinit,
    unsigned short* __restrict__ y)
{
    int tid = threadIdx.x;
    int ch = tid >> 2, ng = tid & 3;
    int bid = blockIdx.x;
    int c = bid & 31, et = (bid >> 5) & 31, b = bid >> 10;
    int e = et * 64 + ch;
    float4 al = *reinterpret_cast<const float4*>(a_log + e * 16 + ng * 4);
    float A0 = -__expf(al.x), A1 = -__expf(al.y), A2 = -__expf(al.z), A3 = -__expf(al.w);
    float dsk = d_skip[e];
    size_t rbase = (size_t)b * 1024 + c * LC;
    const float* dt_p = dt + rbase * 2048 + e;
    const float* u_p  = u  + rbase * 2048 + e;
    const float* z_p  = xz + rbase * 4096 + 2048 + e;
    const float* bc_p = xdbl + rbase * 96 + 64 + ng * 4;
    unsigned short* y_p = y + rbase * 2048 + e;
    size_t oidx = (size_t)c * 65536 + ((size_t)b * 2048 + e) * 16 + ng * 4;
    float4 hi = *reinterpret_cast<const float4*>(hinit + oidx);
    float h0 = hi.x, h1 = hi.y, h2 = hi.z, h3 = hi.w;
    #pragma unroll 4
    for (int l = 0; l < LC; ++l) {
        float dt_v = dt_p[(size_t)l * 2048];
        float u_v  = u_p[(size_t)l * 2048];
        float4 Bv  = *reinterpret_cast<const float4*>(bc_p + (size_t)l * 96);
        float4 Cv  = *reinterpret_cast<const float4*>(bc_p + (size_t)l * 96 + 16);
        float du = dt_v * u_v;
        float d0 = __expf(dt_v * A0), d1 = __expf(dt_v * A1);
        float d2 = __expf(dt_v * A2), d3 = __expf(dt_v * A3);
        h0 = fmaf(d0, h0, du * Bv.x);
        h1 = fmaf(d1, h1, du * Bv.y);
        h2 = fmaf(d2, h2, du * Bv.z);
        h3 = fmaf(d3, h3, du * Bv.w);
        float p = h0 * Cv.x + h1 * Cv.y + h2 * Cv.z + h3 * Cv.w;
        p += __shfl_xor(p, 1);
        p += __shfl_xor(p, 2);
        if (ng == 0) {
            float zv = z_p[(size_t)l * 4096];
            y_p[(size_t)l * 2048] = f2bf((p + u_v * dsk) * siluf(zv));
        }
    }
}

extern "C" void kernel_launch(void* const* d_in, const int* in_sizes, int n_in,
                              void* d_out, int out_size, void* d_ws, size_t ws_size,
                              hipStream_t stream) {
    const float* x       = (const float*)d_in[0];
    const float* ln_w    = (const float*)d_in[1];
    const float* ln_b    = (const float*)d_in[2];
    const float* w_in    = (const float*)d_in[3];
    const float* conv_w  = (const float*)d_in[4];
    const float* conv_b  = (const float*)d_in[5];
    const float* w_xproj = (const float*)d_in[6];
    const float* w_dt    = (const float*)d_in[7];
    const float* b_dt    = (const float*)d_in[8];
    const float* a_log   = (const float*)d_in[9];
    const float* d_skip  = (const float*)d_in[10];
    const float* w_out   = (const float*)d_in[11];
    float* out = (float*)d_out;

    float* ws = (float*)d_ws;
    unsigned short* xn_b    = (unsigned short*)(ws);
    float* xz    = ws + 1048576;
    float* u     = ws + 9437184;
    float* xdbl  = ws + 13631488;
    float* dt    = ws + 13828096;
    float* hpart = ws + 18022400;   // 2M
    float* Aprod = ws + 20119552;   // 2M (spills into dead w_in_b)
    float* hinit = ws + 22216704;   // 2M (spills into w_in_b tail + w_out_b slot)
    float* xpart = ws + 18022400;   // xproj partials (pre-scan alias)
    float* opart = xz;              // out-proj partials (xz dead after part2)
    unsigned short* y_b     = (unsigned short*)(ws + 18022400); // post-combine alias
    unsigned short* w_in_b  = (unsigned short*)(ws + 21168128);
    unsigned short* w_out_b = (unsigned short*)(ws + 23265280); // converted after part2
    unsigned short* w_dt_b  = (unsigned short*)(ws + 24313856);
    unsigned short* dtr_b   = (unsigned short*)(ws + 24379392);

    // 0. weight converts needed before the scan
    f2b_kernel<<<4096, 256, 0, stream>>>(w_in,  w_in_b,  1048576);
    f2b_kernel<<<128,  256, 0, stream>>>(w_dt,  w_dt_b,  32768);
    // 1. LayerNorm -> bf16
    ln_kernel<<<2048, 256, 0, stream>>>(x, ln_w, ln_b, xn_b);
    // 2. xz = xn @ w_in^T   (2048 x 4096 x 1024)  MFMA
    gemm_bf16_nt<<<dim3(32, 16, 1), 256, 0, stream>>>(xn_b, 1024, w_in_b, 1024, 1024,
                                                      xz, 4096, nullptr, nullptr, 0, 0);
    // 3. depthwise conv + silu -> u
    conv_silu_kernel<<<16384, 256, 0, stream>>>(xz, conv_w, conv_b, u);
    // 4. x_dbl = u @ w_xproj^T  (2048 x 96 x 2048)  fp32 split-K
    xproj_splitk<<<dim3(32, 16), 256, 0, stream>>>(u, w_xproj, xpart);
    xproj_reduce<<<768, 256, 0, stream>>>(xpart, xdbl);
    // 4b. dt_r -> bf16
    dtr_kernel<<<128, 256, 0, stream>>>(xdbl, dtr_b);
    // 5. dt = softplus(dt_r @ w_dt^T + b_dt)  MFMA
    gemm_bf16_nt<<<dim3(16, 16, 1), 256, 0, stream>>>(dtr_b, 64, w_dt_b, 64, 64,
                                                      dt, 2048, b_dt, nullptr, 1, 0);
    // 6. chunked selective scan (LC=32, 32 chunks) -> y (bf16)
    scan_part1<<<2048, 256, 0, stream>>>(dt, u, xdbl, a_log, hpart, Aprod);
    scan_combine<<<64, 256, 0, stream>>>(hpart, Aprod, hinit);
    scan_part2<<<2048, 256, 0, stream>>>(dt, u, xdbl, xz, a_log, d_skip, hinit, y_b);
    // 6b. w_out -> bf16 (recycles dead hinit region)
    f2b_kernel<<<2048, 256, 0, stream>>>(w_out, w_out_b, 524288);
    // 7. out-proj split-K x4 + reduce(+residual)
    gemm_bf16_nt<<<dim3(8, 16, 4), 256, 0, stream>>>(y_b, 2048, w_out_b, 2048, 512,
                                                     opart, 1024, nullptr, nullptr, 0, 2097152);
    out_reduce<<<2048, 256, 0, stream>>>(opart, x, out);
}

// Round 8
// 314.365 us; speedup vs baseline: 4.2340x; 1.0111x over previous
//
#include <hip/hip_runtime.h>
#include <hip/hip_bf16.h>

// MambaBlock: B=2, L=1024, dim=1024, d_inner=2048, DT_RANK=64, D_STATE=16
// Inputs fp32, output fp32. MFMA GEMMs use global_load_lds(16B) m97-style staging.
//
// ws layout (float units), with time-multiplexed aliases:
//   xn_b  (bf16 2048x1024) : off 0          size 1,048,576   dead after gemm2
//   xz    (fp32 2048x4096) : off 1,048,576  size 8,388,608   z-half live till part2;
//                                                            out-proj partials alias after
//   u     (fp32 2048x2048) : off 9,437,184  size 4,194,304
//   xdbl  (fp32 2048x96)   : off 13,631,488 size 196,608
//   dt    (fp32 2048x2048) : off 13,828,096 size 4,194,304
//   scan scratch:            hpart @ 18,022,400 (2M)  Aprod @ 20,119,552 (2M)
//                            hinit @ 22,216,704 (2M)
//     y_b (bf16, 2M fu) @ 18,022,400 after combine (hpart/Aprod dead)
//   xpart (16x196608)      : off 18,022,400 (pre-scan alias, xproj partials)
//   w_in_b (bf16)          : off 21,168,128 size 2,097,152   dead after gemm2
//   w_out_b(bf16)          : off 23,265,280 size 1,048,576   converted AFTER part2
//   w_dt_b (bf16 2048x64)  : off 24,313,856 size 65,536
//   dtr_b  (bf16 2048x64)  : off 24,379,392 size 65,536
// total 24,444,928 floats

#define LC 32
#define NCHUNK 32

typedef short bf16x8 __attribute__((ext_vector_type(8)));
typedef float f32x4  __attribute__((ext_vector_type(4)));

static __device__ __forceinline__ float siluf(float x) { return x / (1.f + __expf(-x)); }
static __device__ __forceinline__ unsigned short f2bf(float f) {
    unsigned int u = __float_as_uint(f);
    unsigned int r = (u + 0x7fffu + ((u >> 16) & 1u)) >> 16;
    return (unsigned short)r;
}
// async global->LDS, 16 B per lane; LDS dest = wave-uniform base + lane*16
static __device__ __forceinline__ void gload_lds16(const void* g, void* l) {
    __builtin_amdgcn_global_load_lds(
        (const __attribute__((address_space(1))) void*)g,
        (__attribute__((address_space(3))) void*)l, 16, 0, 0);
}

// ---------------- fp32 -> bf16 convert ----------------
__global__ __launch_bounds__(256) void f2b_kernel(
    const float* __restrict__ in, unsigned short* __restrict__ out, int n4)
{
    int i = blockIdx.x * 256 + threadIdx.x;
    if (i < n4) {
        float4 v = reinterpret_cast<const float4*>(in)[i];
        ushort4 o = { f2bf(v.x), f2bf(v.y), f2bf(v.z), f2bf(v.w) };
        reinterpret_cast<ushort4*>(out)[i] = o;
    }
}

// ---------------- LayerNorm -> bf16 ----------------
__global__ __launch_bounds__(256) void ln_kernel(
    const float* __restrict__ x,
    const float* __restrict__ w,
    const float* __restrict__ bias,
    unsigned short* __restrict__ xn)
{
    int m = blockIdx.x, tid = threadIdx.x;
    const float4* xr = reinterpret_cast<const float4*>(x) + (size_t)m * 256;
    float4 r = xr[tid];
    float f0 = r.x, f1 = r.y, f2 = r.z, f3 = r.w;
    float s  = f0 + f1 + f2 + f3;
    float s2 = f0*f0 + f1*f1 + f2*f2 + f3*f3;
    #pragma unroll
    for (int off = 32; off > 0; off >>= 1) {
        s  += __shfl_down(s, off);
        s2 += __shfl_down(s2, off);
    }
    __shared__ float red[8];
    if ((tid & 63) == 0) { red[tid >> 6] = s; red[4 + (tid >> 6)] = s2; }
    __syncthreads();
    float st = red[0] + red[1] + red[2] + red[3];
    float qt = red[4] + red[5] + red[6] + red[7];
    float mu   = st * (1.f / 1024.f);
    float var  = qt * (1.f / 1024.f) - mu * mu;
    float rstd = rsqrtf(var + 1e-5f);
    float4 wv = reinterpret_cast<const float4*>(w)[tid];
    float4 bv = reinterpret_cast<const float4*>(bias)[tid];
    ushort4 o = { f2bf((f0 - mu) * rstd * wv.x + bv.x),
                  f2bf((f1 - mu) * rstd * wv.y + bv.y),
                  f2bf((f2 - mu) * rstd * wv.z + bv.z),
                  f2bf((f3 - mu) * rstd * wv.w + bv.w) };
    reinterpret_cast<ushort4*>(xn + (size_t)m * 1024)[tid] = o;
}

// ---------------- bf16 MFMA GEMM-NT, global_load_lds staging ----------------
// 128x128 tile, BK=32, 256 threads = 4 waves. Each wave stages 32 rows of A and B
// (2 x 1KiB wave-instructions each). Split-K via gridDim.z.
__global__ __launch_bounds__(256) void gemm_bf16_nt(
    const unsigned short* __restrict__ A, int lda,
    const unsigned short* __restrict__ B, int ldb,
    int Kslice,
    float* __restrict__ C, int ldc,
    const float* __restrict__ bias,
    const float* __restrict__ resid,
    int ep, size_t Cstride)
{
    __shared__ short As[128 * 32];
    __shared__ short Bs[128 * 32];
    int tid = threadIdx.x;
    int z = blockIdx.z;
    A += (size_t)z * Kslice;
    B += (size_t)z * Kslice;
    C += (size_t)z * Cstride;
    int m0 = blockIdx.y * 128, n0 = blockIdx.x * 128;
    int lane = tid & 63, wave = tid >> 6;
    int wm = (wave >> 1) * 64, wn = (wave & 1) * 64;
    int frow = lane & 15, fq = lane >> 4;

    f32x4 acc[4][4] = {};

    // staging: wave w covers rows [w*32, w*32+32); instr j covers 16 rows.
    int srow = wave * 32 + (lane >> 2);      // this lane's global row (j=0)
    int scol = (lane & 3) * 8;               // this lane's 8-element column group
    const unsigned short* AgL = A + (size_t)(m0 + srow) * lda + scol;
    const unsigned short* BgL = B + (size_t)(n0 + srow) * ldb + scol;
    short* AsW = As + wave * 32 * 32;        // wave-uniform LDS base
    short* BsW = Bs + wave * 32 * 32;

    for (int k0 = 0; k0 < Kslice; k0 += 32) {
        __syncthreads();   // prior tile's LDS reads complete before overwrite
        gload_lds16(AgL + k0,                        AsW);
        gload_lds16(AgL + (size_t)16 * lda + k0,     AsW + 16 * 32);
        gload_lds16(BgL + k0,                        BsW);
        gload_lds16(BgL + (size_t)16 * ldb + k0,     BsW + 16 * 32);
        __syncthreads();   // compiler drains vmcnt(0) before barrier -> LDS tile ready
        bf16x8 af[4], bfr[4];
        #pragma unroll
        for (int i = 0; i < 4; ++i)
            af[i] = *reinterpret_cast<const bf16x8*>(As + (wm + i * 16 + frow) * 32 + fq * 8);
        #pragma unroll
        for (int j = 0; j < 4; ++j)
            bfr[j] = *reinterpret_cast<const bf16x8*>(Bs + (wn + j * 16 + frow) * 32 + fq * 8);
        #pragma unroll
        for (int i = 0; i < 4; ++i)
            #pragma unroll
            for (int j = 0; j < 4; ++j)
                acc[i][j] = __builtin_amdgcn_mfma_f32_16x16x32_bf16(af[i], bfr[j], acc[i][j], 0, 0, 0);
    }

    int cn = lane & 15, rq = (lane >> 4) * 4;
    #pragma unroll
    for (int i = 0; i < 4; ++i) {
        #pragma unroll
        for (int j = 0; j < 4; ++j) {
            #pragma unroll
            for (int r = 0; r < 4; ++r) {
                int row = m0 + wm + i * 16 + rq + r;
                int col = n0 + wn + j * 16 + cn;
                float v = acc[i][j][r];
                if (ep == 0) {
                    C[(size_t)row * ldc + col] = v;
                } else if (ep == 1) {
                    v += bias[col];
                    v = (v > 20.f) ? v : log1pf(__expf(v));
                    C[(size_t)row * ldc + col] = v;
                } else {
                    v += resid[(size_t)row * ldc + col];
                    C[(size_t)row * ldc + col] = v;
                }
            }
        }
    }
}

// ---------------- out = x + sum_z part[z] ----------------
__global__ __launch_bounds__(256) void out_reduce(
    const float* __restrict__ part, const float* __restrict__ x,
    float* __restrict__ out)
{
    int i = blockIdx.x * 256 + threadIdx.x;
    float4 s = reinterpret_cast<const float4*>(x)[i];
    #pragma unroll
    for (int z = 0; z < 4; ++z) {
        float4 p = reinterpret_cast<const float4*>(part + (size_t)z * 2097152)[i];
        s.x += p.x; s.y += p.y; s.z += p.z; s.w += p.w;
    }
    reinterpret_cast<float4*>(out)[i] = s;
}

// ---------------- xproj split-K fp32 ----------------
__global__ __launch_bounds__(256) void xproj_splitk(
    const float* __restrict__ A,
    const float* __restrict__ B,
    float* __restrict__ part)
{
    __shared__ float As[16][68];
    __shared__ float Bs[16][100];
    int tid = threadIdx.x;
    int m0 = blockIdx.x * 64;
    int k0 = blockIdx.y * 128;
    int tx = tid & 15;
    int ty = tid >> 4;
    float acc[4][6] = {};
    int arow = tid >> 2, akg = (tid & 3) << 2;
    int brow1 = (256 + tid) >> 2, bkg1 = ((256 + tid) & 3) << 2;

    for (int ks = 0; ks < 128; ks += 16) {
        float4 av = *reinterpret_cast<const float4*>(A + (size_t)(m0 + arow) * 2048 + k0 + ks + akg);
        float4 bv0 = make_float4(0.f, 0.f, 0.f, 0.f), bv1 = bv0;
        if (arow < 96)  bv0 = *reinterpret_cast<const float4*>(B + (size_t)arow * 2048 + k0 + ks + akg);
        if (brow1 < 96) bv1 = *reinterpret_cast<const float4*>(B + (size_t)brow1 * 2048 + k0 + ks + bkg1);
        __syncthreads();
        As[akg + 0][arow] = av.x; As[akg + 1][arow] = av.y;
        As[akg + 2][arow] = av.z; As[akg + 3][arow] = av.w;
        if (arow < 96) {
            Bs[akg + 0][arow] = bv0.x; Bs[akg + 1][arow] = bv0.y;
            Bs[akg + 2][arow] = bv0.z; Bs[akg + 3][arow] = bv0.w;
        }
        if (brow1 < 96) {
            Bs[bkg1 + 0][brow1] = bv1.x; Bs[bkg1 + 1][brow1] = bv1.y;
            Bs[bkg1 + 2][brow1] = bv1.z; Bs[bkg1 + 3][brow1] = bv1.w;
        }
        __syncthreads();
        #pragma unroll
        for (int k = 0; k < 16; ++k) {
            float aa[4], bb[6];
            #pragma unroll
            for (int i = 0; i < 4; ++i) aa[i] = As[k][ty * 4 + i];
            #pragma unroll
            for (int j = 0; j < 6; ++j) bb[j] = Bs[k][tx * 6 + j];
            #pragma unroll
            for (int i = 0; i < 4; ++i)
                #pragma unroll
                for (int j = 0; j < 6; ++j)
                    acc[i][j] = fmaf(aa[i], bb[j], acc[i][j]);
        }
    }
    float* p = part + (size_t)blockIdx.y * 196608;
    #pragma unroll
    for (int i = 0; i < 4; ++i)
        #pragma unroll
        for (int j = 0; j < 6; ++j)
            p[(size_t)(m0 + ty * 4 + i) * 96 + tx * 6 + j] = acc[i][j];
}

// reduce 16 partials -> xdbl; also emit dt_r (cols<64) as bf16
__global__ __launch_bounds__(256) void xproj_reduce(
    const float* __restrict__ part, float* __restrict__ xdbl,
    unsigned short* __restrict__ dtr)
{
    int i = blockIdx.x * 256 + threadIdx.x;   // 196608
    float s = 0.f;
    #pragma unroll
    for (int sd = 0; sd < 16; ++sd) s += part[(size_t)sd * 196608 + i];
    xdbl[i] = s;
    int m = i / 96, col = i - m * 96;
    if (col < 64) dtr[(size_t)m * 64 + col] = f2bf(s);
}

// ---------------- Depthwise causal conv (width 4) + SiLU ----------------
__global__ __launch_bounds__(256) void conv_silu_kernel(
    const float* __restrict__ xz,
    const float* __restrict__ cw,
    const float* __restrict__ cb,
    float* __restrict__ u)
{
    int idx = blockIdx.x * 256 + threadIdx.x;
    int e = idx & 2047;
    int m = idx >> 11;
    int l = m & 1023;
    float acc = cb[e];
    #pragma unroll
    for (int k = 0; k < 4; ++k) {
        int ls = l - 3 + k;
        if (ls >= 0)
            acc += cw[e * 4 + k] * xz[(size_t)(m - 3 + k) * 4096 + e];
    }
    u[(size_t)m * 2048 + e] = siluf(acc);
}

// ---------------- Chunked selective scan: 4 states/lane, LC=32, 32 chunks ----------------
__global__ __launch_bounds__(256) void scan_part1(
    const float* __restrict__ dt,
    const float* __restrict__ u,
    const float* __restrict__ xdbl,
    const float* __restrict__ a_log,
    float* __restrict__ hpart,
    float* __restrict__ Aprod)
{
    int tid = threadIdx.x;
    int ch = tid >> 2, ng = tid & 3;
    int bid = blockIdx.x;
    int c = bid & 31, et = (bid >> 5) & 31, b = bid >> 10;
    int e = et * 64 + ch;
    float4 al = *reinterpret_cast<const float4*>(a_log + e * 16 + ng * 4);
    float A0 = -__expf(al.x), A1 = -__expf(al.y), A2 = -__expf(al.z), A3 = -__expf(al.w);
    size_t rbase = (size_t)b * 1024 + c * LC;
    const float* dt_p = dt + rbase * 2048 + e;
    const float* u_p  = u  + rbase * 2048 + e;
    const float* b_p  = xdbl + rbase * 96 + 64 + ng * 4;
    float h0 = 0.f, h1 = 0.f, h2 = 0.f, h3 = 0.f;
    float P0 = 1.f, P1 = 1.f, P2 = 1.f, P3 = 1.f;
    #pragma unroll 4
    for (int l = 0; l < LC; ++l) {
        float dt_v = dt_p[(size_t)l * 2048];
        float u_v  = u_p[(size_t)l * 2048];
        float4 Bv  = *reinterpret_cast<const float4*>(b_p + (size_t)l * 96);
        float du = dt_v * u_v;
        float d0 = __expf(dt_v * A0), d1 = __expf(dt_v * A1);
        float d2 = __expf(dt_v * A2), d3 = __expf(dt_v * A3);
        h0 = fmaf(d0, h0, du * Bv.x); P0 *= d0;
        h1 = fmaf(d1, h1, du * Bv.y); P1 *= d1;
        h2 = fmaf(d2, h2, du * Bv.z); P2 *= d2;
        h3 = fmaf(d3, h3, du * Bv.w); P3 *= d3;
    }
    size_t oidx = (size_t)c * 65536 + ((size_t)b * 2048 + e) * 16 + ng * 4;
    *reinterpret_cast<float4*>(hpart + oidx) = make_float4(h0, h1, h2, h3);
    *reinterpret_cast<float4*>(Aprod + oidx) = make_float4(P0, P1, P2, P3);
}

__global__ __launch_bounds__(256) void scan_combine(
    const float* __restrict__ hpart,
    const float* __restrict__ Aprod,
    float* __restrict__ hinit)
{
    int t = (blockIdx.x * 256 + threadIdx.x) * 4;
    float4 h = make_float4(0.f, 0.f, 0.f, 0.f);
    #pragma unroll
    for (int c = 0; c < NCHUNK; ++c) {
        *reinterpret_cast<float4*>(hinit + (size_t)c * 65536 + t) = h;
        float4 P = *reinterpret_cast<const float4*>(Aprod + (size_t)c * 65536 + t);
        float4 hp = *reinterpret_cast<const float4*>(hpart + (size_t)c * 65536 + t);
        h.x = fmaf(P.x, h.x, hp.x);
        h.y = fmaf(P.y, h.y, hp.y);
        h.z = fmaf(P.z, h.z, hp.z);
        h.w = fmaf(P.w, h.w, hp.w);
    }
}

__global__ __launch_bounds__(256) void scan_part2(
    const float* __restrict__ dt,
    const float* __restrict__ u,
    const float* __restrict__ xdbl,
    const float* __restrict__ xz,
    const float* __restrict__ a_log,
    const float* __restrict__ d_skip,
    const float* __restrict__ hinit,
    unsigned short* __restrict__ y)
{
    int tid = threadIdx.x;
    int ch = tid >> 2, ng = tid & 3;
    int bid = blockIdx.x;
    int c = bid & 31, et = (bid >> 5) & 31, b = bid >> 10;
    int e = et * 64 + ch;
    float4 al = *reinterpret_cast<const float4*>(a_log + e * 16 + ng * 4);
    float A0 = -__expf(al.x), A1 = -__expf(al.y), A2 = -__expf(al.z), A3 = -__expf(al.w);
    float dsk = d_skip[e];
    size_t rbase = (size_t)b * 1024 + c * LC;
    const float* dt_p = dt + rbase * 2048 + e;
    const float* u_p  = u  + rbase * 2048 + e;
    const float* z_p  = xz + rbase * 4096 + 2048 + e;
    const float* bc_p = xdbl + rbase * 96 + 64 + ng * 4;
    unsigned short* y_p = y + rbase * 2048 + e;
    size_t oidx = (size_t)c * 65536 + ((size_t)b * 2048 + e) * 16 + ng * 4;
    float4 hi = *reinterpret_cast<const float4*>(hinit + oidx);
    float h0 = hi.x, h1 = hi.y, h2 = hi.z, h3 = hi.w;
    #pragma unroll 4
    for (int l = 0; l < LC; ++l) {
        float dt_v = dt_p[(size_t)l * 2048];
        float u_v  = u_p[(size_t)l * 2048];
        float4 Bv  = *reinterpret_cast<const float4*>(bc_p + (size_t)l * 96);
        float4 Cv  = *reinterpret_cast<const float4*>(bc_p + (size_t)l * 96 + 16);
        float du = dt_v * u_v;
        float d0 = __expf(dt_v * A0), d1 = __expf(dt_v * A1);
        float d2 = __expf(dt_v * A2), d3 = __expf(dt_v * A3);
        h0 = fmaf(d0, h0, du * Bv.x);
        h1 = fmaf(d1, h1, du * Bv.y);
        h2 = fmaf(d2, h2, du * Bv.z);
        h3 = fmaf(d3, h3, du * Bv.w);
        float p = h0 * Cv.x + h1 * Cv.y + h2 * Cv.z + h3 * Cv.w;
        p += __shfl_xor(p, 1);
        p += __shfl_xor(p, 2);
        if (ng == 0) {
            float zv = z_p[(size_t)l * 4096];
            y_p[(size_t)l * 2048] = f2bf((p + u_v * dsk) * siluf(zv));
        }
    }
}

extern "C" void kernel_launch(void* const* d_in, const int* in_sizes, int n_in,
                              void* d_out, int out_size, void* d_ws, size_t ws_size,
                              hipStream_t stream) {
    const float* x       = (const float*)d_in[0];
    const float* ln_w    = (const float*)d_in[1];
    const float* ln_b    = (const float*)d_in[2];
    const float* w_in    = (const float*)d_in[3];
    const float* conv_w  = (const float*)d_in[4];
    const float* conv_b  = (const float*)d_in[5];
    const float* w_xproj = (const float*)d_in[6];
    const float* w_dt    = (const float*)d_in[7];
    const float* b_dt    = (const float*)d_in[8];
    const float* a_log   = (const float*)d_in[9];
    const float* d_skip  = (const float*)d_in[10];
    const float* w_out   = (const float*)d_in[11];
    float* out = (float*)d_out;

    float* ws = (float*)d_ws;
    unsigned short* xn_b    = (unsigned short*)(ws);
    float* xz    = ws + 1048576;
    float* u     = ws + 9437184;
    float* xdbl  = ws + 13631488;
    float* dt    = ws + 13828096;
    float* hpart = ws + 18022400;   // 2M
    float* Aprod = ws + 20119552;   // 2M (spills into dead w_in_b)
    float* hinit = ws + 22216704;   // 2M
    float* xpart = ws + 18022400;   // xproj partials (pre-scan alias)
    float* opart = xz;              // out-proj partials (xz dead after part2)
    unsigned short* y_b     = (unsigned short*)(ws + 18022400); // post-combine alias
    unsigned short* w_in_b  = (unsigned short*)(ws + 21168128);
    unsigned short* w_out_b = (unsigned short*)(ws + 23265280); // converted after part2
    unsigned short* w_dt_b  = (unsigned short*)(ws + 24313856);
    unsigned short* dtr_b   = (unsigned short*)(ws + 24379392);

    // 0. weight converts needed before the scan
    f2b_kernel<<<4096, 256, 0, stream>>>(w_in,  w_in_b,  1048576);
    f2b_kernel<<<128,  256, 0, stream>>>(w_dt,  w_dt_b,  32768);
    // 1. LayerNorm -> bf16
    ln_kernel<<<2048, 256, 0, stream>>>(x, ln_w, ln_b, xn_b);
    // 2. xz = xn @ w_in^T   (2048 x 4096 x 1024)  MFMA
    gemm_bf16_nt<<<dim3(32, 16, 1), 256, 0, stream>>>(xn_b, 1024, w_in_b, 1024, 1024,
                                                      xz, 4096, nullptr, nullptr, 0, 0);
    // 3. depthwise conv + silu -> u
    conv_silu_kernel<<<16384, 256, 0, stream>>>(xz, conv_w, conv_b, u);
    // 4. x_dbl = u @ w_xproj^T  (2048 x 96 x 2048)  fp32 split-K; reduce also emits dt_r bf16
    xproj_splitk<<<dim3(32, 16), 256, 0, stream>>>(u, w_xproj, xpart);
    xproj_reduce<<<768, 256, 0, stream>>>(xpart, xdbl, dtr_b);
    // 5. dt = softplus(dt_r @ w_dt^T + b_dt)  MFMA
    gemm_bf16_nt<<<dim3(16, 16, 1), 256, 0, stream>>>(dtr_b, 64, w_dt_b, 64, 64,
                                                      dt, 2048, b_dt, nullptr, 1, 0);
    // 6. chunked selective scan (LC=32, 32 chunks) -> y (bf16)
    scan_part1<<<2048, 256, 0, stream>>>(dt, u, xdbl, a_log, hpart, Aprod);
    scan_combine<<<64, 256, 0, stream>>>(hpart, Aprod, hinit);
    scan_part2<<<2048, 256, 0, stream>>>(dt, u, xdbl, xz, a_log, d_skip, hinit, y_b);
    // 6b. w_out -> bf16 (recycles dead region)
    f2b_kernel<<<2048, 256, 0, stream>>>(w_out, w_out_b, 524288);
    // 7. out-proj split-K x4 + reduce(+residual)
    gemm_bf16_nt<<<dim3(8, 16, 4), 256, 0, stream>>>(y_b, 2048, w_out_b, 2048, 512,
                                                     opart, 1024, nullptr, nullptr, 0, 2097152);
    out_reduce<<<2048, 256, 0, stream>>>(opart, x, out);
}

// Round 9
// 285.397 us; speedup vs baseline: 4.6638x; 1.1015x over previous
//
#include <hip/hip_runtime.h>
#include <hip/hip_bf16.h>

// MambaBlock: B=2, L=1024, dim=1024, d_inner=2048, DT_RANK=64, D_STATE=16
// Inputs fp32, output fp32. MFMA GEMMs: 128x64 tile, BK=32, global_load_lds staging.
//
// ws layout (float units), with time-multiplexed aliases:
//   xn_b  (bf16 2048x1024) : off 0          size 1,048,576   dead after gemm2
//   xz    (fp32 2048x4096) : off 1,048,576  size 8,388,608   z-half live till part2;
//                                                            out-proj partials alias after
//   u     (fp32 2048x2048) : off 9,437,184  size 4,194,304
//   xdbl  (fp32 2048x96)   : off 13,631,488 size 196,608
//   dt    (fp32 2048x2048) : off 13,828,096 size 4,194,304
//   scan scratch:            hpart @ 18,022,400 (2M)  Aprod @ 20,119,552 (2M)
//                            hinit @ 22,216,704 (2M)
//     y_b (bf16, 2M fu) @ 18,022,400 after combine (hpart/Aprod dead)
//   xpart (16x196608)      : off 18,022,400 (pre-scan alias, xproj partials)
//   w_in_b (bf16)          : off 21,168,128 size 2,097,152   dead after gemm2
//   w_out_b(bf16)          : off 23,265,280 size 1,048,576   converted AFTER part2
//   w_dt_b (bf16 2048x64)  : off 24,313,856 size 65,536
//   dtr_b  (bf16 2048x64)  : off 24,379,392 size 65,536
// total 24,444,928 floats

#define LC 32
#define NCHUNK 32

typedef short bf16x8 __attribute__((ext_vector_type(8)));
typedef float f32x4  __attribute__((ext_vector_type(4)));

static __device__ __forceinline__ float siluf(float x) { return x / (1.f + __expf(-x)); }
static __device__ __forceinline__ unsigned short f2bf(float f) {
    unsigned int u = __float_as_uint(f);
    unsigned int r = (u + 0x7fffu + ((u >> 16) & 1u)) >> 16;
    return (unsigned short)r;
}
// async global->LDS, 16 B per lane; LDS dest = wave-uniform base + lane*16
static __device__ __forceinline__ void gload_lds16(const void* g, void* l) {
    __builtin_amdgcn_global_load_lds(
        (const __attribute__((address_space(1))) void*)g,
        (__attribute__((address_space(3))) void*)l, 16, 0, 0);
}

// ---------------- fp32 -> bf16 convert (dual range: w_in then w_dt) ----------------
__global__ __launch_bounds__(256) void f2b_dual(
    const float* __restrict__ in0, unsigned short* __restrict__ out0, int n0,
    const float* __restrict__ in1, unsigned short* __restrict__ out1, int n1)
{
    int i = blockIdx.x * 256 + threadIdx.x;
    if (i < n0) {
        float4 v = reinterpret_cast<const float4*>(in0)[i];
        ushort4 o = { f2bf(v.x), f2bf(v.y), f2bf(v.z), f2bf(v.w) };
        reinterpret_cast<ushort4*>(out0)[i] = o;
    } else if (i - n0 < n1) {
        int j = i - n0;
        float4 v = reinterpret_cast<const float4*>(in1)[j];
        ushort4 o = { f2bf(v.x), f2bf(v.y), f2bf(v.z), f2bf(v.w) };
        reinterpret_cast<ushort4*>(out1)[j] = o;
    }
}

__global__ __launch_bounds__(256) void f2b_kernel(
    const float* __restrict__ in, unsigned short* __restrict__ out, int n4)
{
    int i = blockIdx.x * 256 + threadIdx.x;
    if (i < n4) {
        float4 v = reinterpret_cast<const float4*>(in)[i];
        ushort4 o = { f2bf(v.x), f2bf(v.y), f2bf(v.z), f2bf(v.w) };
        reinterpret_cast<ushort4*>(out)[i] = o;
    }
}

// ---------------- LayerNorm -> bf16 ----------------
__global__ __launch_bounds__(256) void ln_kernel(
    const float* __restrict__ x,
    const float* __restrict__ w,
    const float* __restrict__ bias,
    unsigned short* __restrict__ xn)
{
    int m = blockIdx.x, tid = threadIdx.x;
    const float4* xr = reinterpret_cast<const float4*>(x) + (size_t)m * 256;
    float4 r = xr[tid];
    float f0 = r.x, f1 = r.y, f2 = r.z, f3 = r.w;
    float s  = f0 + f1 + f2 + f3;
    float s2 = f0*f0 + f1*f1 + f2*f2 + f3*f3;
    #pragma unroll
    for (int off = 32; off > 0; off >>= 1) {
        s  += __shfl_down(s, off);
        s2 += __shfl_down(s2, off);
    }
    __shared__ float red[8];
    if ((tid & 63) == 0) { red[tid >> 6] = s; red[4 + (tid >> 6)] = s2; }
    __syncthreads();
    float st = red[0] + red[1] + red[2] + red[3];
    float qt = red[4] + red[5] + red[6] + red[7];
    float mu   = st * (1.f / 1024.f);
    float var  = qt * (1.f / 1024.f) - mu * mu;
    float rstd = rsqrtf(var + 1e-5f);
    float4 wv = reinterpret_cast<const float4*>(w)[tid];
    float4 bv = reinterpret_cast<const float4*>(bias)[tid];
    ushort4 o = { f2bf((f0 - mu) * rstd * wv.x + bv.x),
                  f2bf((f1 - mu) * rstd * wv.y + bv.y),
                  f2bf((f2 - mu) * rstd * wv.z + bv.z),
                  f2bf((f3 - mu) * rstd * wv.w + bv.w) };
    reinterpret_cast<ushort4*>(xn + (size_t)m * 1024)[tid] = o;
}

// ---------------- bf16 MFMA GEMM-NT, 128x64 tile, global_load_lds staging ----------
// 256 threads = 4 waves in 2x2 (wm in {0,64}, wn in {0,32}); each wave 64x32 out.
// Per K-iter: each wave stages 32 A-rows (2 instr) + 16 B-rows (1 instr).
__global__ __launch_bounds__(256) void gemm_bf16_nt(
    const unsigned short* __restrict__ A, int lda,
    const unsigned short* __restrict__ B, int ldb,
    int Kslice,
    float* __restrict__ C, int ldc,
    const float* __restrict__ bias,
    const float* __restrict__ resid,
    int ep, size_t Cstride)
{
    __shared__ short As[128 * 32];   // 8 KB
    __shared__ short Bs[64 * 32];    // 4 KB
    int tid = threadIdx.x;
    int z = blockIdx.z;
    A += (size_t)z * Kslice;
    B += (size_t)z * Kslice;
    C += (size_t)z * Cstride;
    int m0 = blockIdx.y * 128, n0 = blockIdx.x * 64;
    int lane = tid & 63, wave = tid >> 6;
    int wm = (wave >> 1) * 64, wn = (wave & 1) * 32;
    int frow = lane & 15, fq = lane >> 4;

    f32x4 acc[4][2] = {};

    // staging lane mapping: 16 rows per instr, lane>>2 = row, (lane&3)*8 = col
    int lrow = lane >> 2;
    int scol = (lane & 3) * 8;
    const unsigned short* AgL = A + (size_t)(m0 + wave * 32 + lrow) * lda + scol;
    const unsigned short* BgL = B + (size_t)(n0 + wave * 16 + lrow) * ldb + scol;
    short* AsW = As + (wave * 32) * 32;
    short* BsW = Bs + (wave * 16) * 32;

    for (int k0 = 0; k0 < Kslice; k0 += 32) {
        __syncthreads();
        gload_lds16(AgL + k0,                     AsW);
        gload_lds16(AgL + (size_t)16 * lda + k0,  AsW + 16 * 32);
        gload_lds16(BgL + k0,                     BsW);
        __syncthreads();
        bf16x8 af[4], bfr[2];
        #pragma unroll
        for (int i = 0; i < 4; ++i)
            af[i] = *reinterpret_cast<const bf16x8*>(As + (wm + i * 16 + frow) * 32 + fq * 8);
        #pragma unroll
        for (int j = 0; j < 2; ++j)
            bfr[j] = *reinterpret_cast<const bf16x8*>(Bs + (wn + j * 16 + frow) * 32 + fq * 8);
        #pragma unroll
        for (int i = 0; i < 4; ++i)
            #pragma unroll
            for (int j = 0; j < 2; ++j)
                acc[i][j] = __builtin_amdgcn_mfma_f32_16x16x32_bf16(af[i], bfr[j], acc[i][j], 0, 0, 0);
    }

    int cn = lane & 15, rq = (lane >> 4) * 4;
    #pragma unroll
    for (int i = 0; i < 4; ++i) {
        #pragma unroll
        for (int j = 0; j < 2; ++j) {
            #pragma unroll
            for (int r = 0; r < 4; ++r) {
                int row = m0 + wm + i * 16 + rq + r;
                int col = n0 + wn + j * 16 + cn;
                float v = acc[i][j][r];
                if (ep == 0) {
                    C[(size_t)row * ldc + col] = v;
                } else if (ep == 1) {
                    v += bias[col];
                    v = (v > 20.f) ? v : log1pf(__expf(v));
                    C[(size_t)row * ldc + col] = v;
                } else {
                    v += resid[(size_t)row * ldc + col];
                    C[(size_t)row * ldc + col] = v;
                }
            }
        }
    }
}

// ---------------- out = x + sum_z part[z] ----------------
__global__ __launch_bounds__(256) void out_reduce(
    const float* __restrict__ part, const float* __restrict__ x,
    float* __restrict__ out)
{
    int i = blockIdx.x * 256 + threadIdx.x;
    float4 s = reinterpret_cast<const float4*>(x)[i];
    #pragma unroll
    for (int z = 0; z < 4; ++z) {
        float4 p = reinterpret_cast<const float4*>(part + (size_t)z * 2097152)[i];
        s.x += p.x; s.y += p.y; s.z += p.z; s.w += p.w;
    }
    reinterpret_cast<float4*>(out)[i] = s;
}

// ---------------- xproj split-K fp32 ----------------
__global__ __launch_bounds__(256) void xproj_splitk(
    const float* __restrict__ A,
    const float* __restrict__ B,
    float* __restrict__ part)
{
    __shared__ float As[16][68];
    __shared__ float Bs[16][100];
    int tid = threadIdx.x;
    int m0 = blockIdx.x * 64;
    int k0 = blockIdx.y * 128;
    int tx = tid & 15;
    int ty = tid >> 4;
    float acc[4][6] = {};
    int arow = tid >> 2, akg = (tid & 3) << 2;
    int brow1 = (256 + tid) >> 2, bkg1 = ((256 + tid) & 3) << 2;

    for (int ks = 0; ks < 128; ks += 16) {
        float4 av = *reinterpret_cast<const float4*>(A + (size_t)(m0 + arow) * 2048 + k0 + ks + akg);
        float4 bv0 = make_float4(0.f, 0.f, 0.f, 0.f), bv1 = bv0;
        if (arow < 96)  bv0 = *reinterpret_cast<const float4*>(B + (size_t)arow * 2048 + k0 + ks + akg);
        if (brow1 < 96) bv1 = *reinterpret_cast<const float4*>(B + (size_t)brow1 * 2048 + k0 + ks + bkg1);
        __syncthreads();
        As[akg + 0][arow] = av.x; As[akg + 1][arow] = av.y;
        As[akg + 2][arow] = av.z; As[akg + 3][arow] = av.w;
        if (arow < 96) {
            Bs[akg + 0][arow] = bv0.x; Bs[akg + 1][arow] = bv0.y;
            Bs[akg + 2][arow] = bv0.z; Bs[akg + 3][arow] = bv0.w;
        }
        if (brow1 < 96) {
            Bs[bkg1 + 0][brow1] = bv1.x; Bs[bkg1 + 1][brow1] = bv1.y;
            Bs[bkg1 + 2][brow1] = bv1.z; Bs[bkg1 + 3][brow1] = bv1.w;
        }
        __syncthreads();
        #pragma unroll
        for (int k = 0; k < 16; ++k) {
            float aa[4], bb[6];
            #pragma unroll
            for (int i = 0; i < 4; ++i) aa[i] = As[k][ty * 4 + i];
            #pragma unroll
            for (int j = 0; j < 6; ++j) bb[j] = Bs[k][tx * 6 + j];
            #pragma unroll
            for (int i = 0; i < 4; ++i)
                #pragma unroll
                for (int j = 0; j < 6; ++j)
                    acc[i][j] = fmaf(aa[i], bb[j], acc[i][j]);
        }
    }
    float* p = part + (size_t)blockIdx.y * 196608;
    #pragma unroll
    for (int i = 0; i < 4; ++i)
        #pragma unroll
        for (int j = 0; j < 6; ++j)
            p[(size_t)(m0 + ty * 4 + i) * 96 + tx * 6 + j] = acc[i][j];
}

// reduce 16 partials -> xdbl; also emit dt_r (cols<64) as bf16
__global__ __launch_bounds__(256) void xproj_reduce(
    const float* __restrict__ part, float* __restrict__ xdbl,
    unsigned short* __restrict__ dtr)
{
    int i = blockIdx.x * 256 + threadIdx.x;   // 196608
    float s = 0.f;
    #pragma unroll
    for (int sd = 0; sd < 16; ++sd) s += part[(size_t)sd * 196608 + i];
    xdbl[i] = s;
    int m = i / 96, col = i - m * 96;
    if (col < 64) dtr[(size_t)m * 64 + col] = f2bf(s);
}

// ---------------- Depthwise causal conv (width 4) + SiLU ----------------
__global__ __launch_bounds__(256) void conv_silu_kernel(
    const float* __restrict__ xz,
    const float* __restrict__ cw,
    const float* __restrict__ cb,
    float* __restrict__ u)
{
    int idx = blockIdx.x * 256 + threadIdx.x;
    int e = idx & 2047;
    int m = idx >> 11;
    int l = m & 1023;
    float acc = cb[e];
    #pragma unroll
    for (int k = 0; k < 4; ++k) {
        int ls = l - 3 + k;
        if (ls >= 0)
            acc += cw[e * 4 + k] * xz[(size_t)(m - 3 + k) * 4096 + e];
    }
    u[(size_t)m * 2048 + e] = siluf(acc);
}

// ---------------- Chunked selective scan: 4 states/lane, LC=32, 32 chunks ----------------
__global__ __launch_bounds__(256) void scan_part1(
    const float* __restrict__ dt,
    const float* __restrict__ u,
    const float* __restrict__ xdbl,
    const float* __restrict__ a_log,
    float* __restrict__ hpart,
    float* __restrict__ Aprod)
{
    int tid = threadIdx.x;
    int ch = tid >> 2, ng = tid & 3;
    int bid = blockIdx.x;
    int c = bid & 31, et = (bid >> 5) & 31, b = bid >> 10;
    int e = et * 64 + ch;
    float4 al = *reinterpret_cast<const float4*>(a_log + e * 16 + ng * 4);
    float A0 = -__expf(al.x), A1 = -__expf(al.y), A2 = -__expf(al.z), A3 = -__expf(al.w);
    size_t rbase = (size_t)b * 1024 + c * LC;
    const float* dt_p = dt + rbase * 2048 + e;
    const float* u_p  = u  + rbase * 2048 + e;
    const float* b_p  = xdbl + rbase * 96 + 64 + ng * 4;
    float h0 = 0.f, h1 = 0.f, h2 = 0.f, h3 = 0.f;
    float P0 = 1.f, P1 = 1.f, P2 = 1.f, P3 = 1.f;
    #pragma unroll 4
    for (int l = 0; l < LC; ++l) {
        float dt_v = dt_p[(size_t)l * 2048];
        float u_v  = u_p[(size_t)l * 2048];
        float4 Bv  = *reinterpret_cast<const float4*>(b_p + (size_t)l * 96);
        float du = dt_v * u_v;
        float d0 = __expf(dt_v * A0), d1 = __expf(dt_v * A1);
        float d2 = __expf(dt_v * A2), d3 = __expf(dt_v * A3);
        h0 = fmaf(d0, h0, du * Bv.x); P0 *= d0;
        h1 = fmaf(d1, h1, du * Bv.y); P1 *= d1;
        h2 = fmaf(d2, h2, du * Bv.z); P2 *= d2;
        h3 = fmaf(d3, h3, du * Bv.w); P3 *= d3;
    }
    size_t oidx = (size_t)c * 65536 + ((size_t)b * 2048 + e) * 16 + ng * 4;
    *reinterpret_cast<float4*>(hpart + oidx) = make_float4(h0, h1, h2, h3);
    *reinterpret_cast<float4*>(Aprod + oidx) = make_float4(P0, P1, P2, P3);
}

__global__ __launch_bounds__(256) void scan_combine(
    const float* __restrict__ hpart,
    const float* __restrict__ Aprod,
    float* __restrict__ hinit)
{
    int t = (blockIdx.x * 256 + threadIdx.x) * 4;
    float4 h = make_float4(0.f, 0.f, 0.f, 0.f);
    #pragma unroll
    for (int c = 0; c < NCHUNK; ++c) {
        *reinterpret_cast<float4*>(hinit + (size_t)c * 65536 + t) = h;
        float4 P = *reinterpret_cast<const float4*>(Aprod + (size_t)c * 65536 + t);
        float4 hp = *reinterpret_cast<const float4*>(hpart + (size_t)c * 65536 + t);
        h.x = fmaf(P.x, h.x, hp.x);
        h.y = fmaf(P.y, h.y, hp.y);
        h.z = fmaf(P.z, h.z, hp.z);
        h.w = fmaf(P.w, h.w, hp.w);
    }
}

__global__ __launch_bounds__(256) void scan_part2(
    const float* __restrict__ dt,
    const float* __restrict__ u,
    const float* __restrict__ xdbl,
    const float* __restrict__ xz,
    const float* __restrict__ a_log,
    const float* __restrict__ d_skip,
    const float* __restrict__ hinit,
    unsigned short* __restrict__ y)
{
    int tid = threadIdx.x;
    int ch = tid >> 2, ng = tid & 3;
    int bid = blockIdx.x;
    int c = bid & 31, et = (bid >> 5) & 31, b = bid >> 10;
    int e = et * 64 + ch;
    float4 al = *reinterpret_cast<const float4*>(a_log + e * 16 + ng * 4);
    float A0 = -__expf(al.x), A1 = -__expf(al.y), A2 = -__expf(al.z), A3 = -__expf(al.w);
    float dsk = d_skip[e];
    size_t rbase = (size_t)b * 1024 + c * LC;
    const float* dt_p = dt + rbase * 2048 + e;
    const float* u_p  = u  + rbase * 2048 + e;
    const float* z_p  = xz + rbase * 4096 + 2048 + e;
    const float* bc_p = xdbl + rbase * 96 + 64 + ng * 4;
    unsigned short* y_p = y + rbase * 2048 + e;
    size_t oidx = (size_t)c * 65536 + ((size_t)b * 2048 + e) * 16 + ng * 4;
    float4 hi = *reinterpret_cast<const float4*>(hinit + oidx);
    float h0 = hi.x, h1 = hi.y, h2 = hi.z, h3 = hi.w;
    #pragma unroll 4
    for (int l = 0; l < LC; ++l) {
        float dt_v = dt_p[(size_t)l * 2048];
        float u_v  = u_p[(size_t)l * 2048];
        float4 Bv  = *reinterpret_cast<const float4*>(bc_p + (size_t)l * 96);
        float4 Cv  = *reinterpret_cast<const float4*>(bc_p + (size_t)l * 96 + 16);
        float du = dt_v * u_v;
        float d0 = __expf(dt_v * A0), d1 = __expf(dt_v * A1);
        float d2 = __expf(dt_v * A2), d3 = __expf(dt_v * A3);
        h0 = fmaf(d0, h0, du * Bv.x);
        h1 = fmaf(d1, h1, du * Bv.y);
        h2 = fmaf(d2, h2, du * Bv.z);
        h3 = fmaf(d3, h3, du * Bv.w);
        float p = h0 * Cv.x + h1 * Cv.y + h2 * Cv.z + h3 * Cv.w;
        p += __shfl_xor(p, 1);
        p += __shfl_xor(p, 2);
        if (ng == 0) {
            float zv = z_p[(size_t)l * 4096];
            y_p[(size_t)l * 2048] = f2bf((p + u_v * dsk) * siluf(zv));
        }
    }
}

extern "C" void kernel_launch(void* const* d_in, const int* in_sizes, int n_in,
                              void* d_out, int out_size, void* d_ws, size_t ws_size,
                              hipStream_t stream) {
    const float* x       = (const float*)d_in[0];
    const float* ln_w    = (const float*)d_in[1];
    const float* ln_b    = (const float*)d_in[2];
    const float* w_in    = (const float*)d_in[3];
    const float* conv_w  = (const float*)d_in[4];
    const float* conv_b  = (const float*)d_in[5];
    const float* w_xproj = (const float*)d_in[6];
    const float* w_dt    = (const float*)d_in[7];
    const float* b_dt    = (const float*)d_in[8];
    const float* a_log   = (const float*)d_in[9];
    const float* d_skip  = (const float*)d_in[10];
    const float* w_out   = (const float*)d_in[11];
    float* out = (float*)d_out;

    float* ws = (float*)d_ws;
    unsigned short* xn_b    = (unsigned short*)(ws);
    float* xz    = ws + 1048576;
    float* u     = ws + 9437184;
    float* xdbl  = ws + 13631488;
    float* dt    = ws + 13828096;
    float* hpart = ws + 18022400;   // 2M
    float* Aprod = ws + 20119552;   // 2M (spills into dead w_in_b)
    float* hinit = ws + 22216704;   // 2M
    float* xpart = ws + 18022400;   // xproj partials (pre-scan alias)
    float* opart = xz;              // out-proj partials (xz dead after part2)
    unsigned short* y_b     = (unsigned short*)(ws + 18022400); // post-combine alias
    unsigned short* w_in_b  = (unsigned short*)(ws + 21168128);
    unsigned short* w_out_b = (unsigned short*)(ws + 23265280); // converted after part2
    unsigned short* w_dt_b  = (unsigned short*)(ws + 24313856);
    unsigned short* dtr_b   = (unsigned short*)(ws + 24379392);

    // 0. weight converts needed before the scan (single launch)
    f2b_dual<<<4224, 256, 0, stream>>>(w_in, w_in_b, 1048576, w_dt, w_dt_b, 32768);
    // 1. LayerNorm -> bf16
    ln_kernel<<<2048, 256, 0, stream>>>(x, ln_w, ln_b, xn_b);
    // 2. xz = xn @ w_in^T   (2048 x 4096 x 1024)  MFMA, 128x64 tiles -> 1024 blocks
    gemm_bf16_nt<<<dim3(64, 16, 1), 256, 0, stream>>>(xn_b, 1024, w_in_b, 1024, 1024,
                                                      xz, 4096, nullptr, nullptr, 0, 0);
    // 3. depthwise conv + silu -> u
    conv_silu_kernel<<<16384, 256, 0, stream>>>(xz, conv_w, conv_b, u);
    // 4. x_dbl = u @ w_xproj^T  (2048 x 96 x 2048)  fp32 split-K; reduce also emits dt_r bf16
    xproj_splitk<<<dim3(32, 16), 256, 0, stream>>>(u, w_xproj, xpart);
    xproj_reduce<<<768, 256, 0, stream>>>(xpart, xdbl, dtr_b);
    // 5. dt = softplus(dt_r @ w_dt^T + b_dt)  MFMA -> 512 blocks
    gemm_bf16_nt<<<dim3(32, 16, 1), 256, 0, stream>>>(dtr_b, 64, w_dt_b, 64, 64,
                                                      dt, 2048, b_dt, nullptr, 1, 0);
    // 6. chunked selective scan (LC=32, 32 chunks) -> y (bf16)
    scan_part1<<<2048, 256, 0, stream>>>(dt, u, xdbl, a_log, hpart, Aprod);
    scan_combine<<<64, 256, 0, stream>>>(hpart, Aprod, hinit);
    scan_part2<<<2048, 256, 0, stream>>>(dt, u, xdbl, xz, a_log, d_skip, hinit, y_b);
    // 6b. w_out -> bf16
    f2b_kernel<<<2048, 256, 0, stream>>>(w_out, w_out_b, 524288);
    // 7. out-proj split-K x4 (128x64 tiles -> 1024 blocks) + reduce(+residual)
    gemm_bf16_nt<<<dim3(16, 16, 4), 256, 0, stream>>>(y_b, 2048, w_out_b, 2048, 512,
                                                      opart, 1024, nullptr, nullptr, 0, 2097152);
    out_reduce<<<2048, 256, 0, stream>>>(opart, x, out);
}

// Round 10
// 279.648 us; speedup vs baseline: 4.7597x; 1.0206x over previous
//
#include <hip/hip_runtime.h>
#include <hip/hip_bf16.h>

// MambaBlock: B=2, L=1024, dim=1024, d_inner=2048, DT_RANK=64, D_STATE=16
// Inputs fp32, output fp32. MFMA GEMMs: 128x64 tile, BK=32, dbuf single-barrier
// K-loop with global_load_lds staging. Scan: depth-2 software pipeline.
//
// ws layout (float units), with time-multiplexed aliases:
//   xn_b  (bf16 2048x1024) : off 0          size 1,048,576   dead after gemm2
//   xz    (fp32 2048x4096) : off 1,048,576  size 8,388,608   z-half live till part2;
//                                                            out-proj partials alias after
//   u     (fp32 2048x2048) : off 9,437,184  size 4,194,304
//   xdbl  (fp32 2048x96)   : off 13,631,488 size 196,608
//   dt    (fp32 2048x2048) : off 13,828,096 size 4,194,304
//   scan scratch:            hpart @ 18,022,400 (2M)  Aprod @ 20,119,552 (2M)
//                            hinit @ 22,216,704 (2M)
//     y_b (bf16, 2M fu) @ 18,022,400 after combine (hpart/Aprod dead)
//   xpart (16x196608)      : off 18,022,400 (pre-scan alias, xproj partials)
//   w_in_b (bf16)          : off 21,168,128 size 2,097,152   dead after gemm2
//   w_dt_b (bf16 2048x64)  : off 24,313,856 size 65,536
//   dtr_b  (bf16 2048x64)  : off 24,379,392 size 65,536
//   w_out_b(bf16 1024x2048): off 24,444,928 size 1,048,576   (no alias; converted upfront)
// total 25,493,504 floats (~97.2 MB; R3 used 100.8 MB OK)

#define LC 32
#define NCHUNK 32

typedef short bf16x8 __attribute__((ext_vector_type(8)));
typedef float f32x4  __attribute__((ext_vector_type(4)));

static __device__ __forceinline__ float siluf(float x) { return x / (1.f + __expf(-x)); }
static __device__ __forceinline__ unsigned short f2bf(float f) {
    unsigned int u = __float_as_uint(f);
    unsigned int r = (u + 0x7fffu + ((u >> 16) & 1u)) >> 16;
    return (unsigned short)r;
}
// async global->LDS, 16 B per lane; LDS dest = wave-uniform base + lane*16
static __device__ __forceinline__ void gload_lds16(const void* g, void* l) {
    __builtin_amdgcn_global_load_lds(
        (const __attribute__((address_space(1))) void*)g,
        (__attribute__((address_space(3))) void*)l, 16, 0, 0);
}

// ---------------- fp32 -> bf16 convert: all three weights in one launch ----------------
__global__ __launch_bounds__(256) void f2b_all(
    const float* __restrict__ w_in,  unsigned short* __restrict__ w_in_b,
    const float* __restrict__ w_out, unsigned short* __restrict__ w_out_b,
    const float* __restrict__ w_dt,  unsigned short* __restrict__ w_dt_b)
{
    int i = blockIdx.x * 256 + threadIdx.x;
    const float* in; unsigned short* outp; int j;
    if (i < 1048576)      { in = w_in;  outp = w_in_b;  j = i; }
    else if (i < 1572864) { in = w_out; outp = w_out_b; j = i - 1048576; }
    else if (i < 1605632) { in = w_dt;  outp = w_dt_b;  j = i - 1572864; }
    else return;
    float4 v = reinterpret_cast<const float4*>(in)[j];
    ushort4 o = { f2bf(v.x), f2bf(v.y), f2bf(v.z), f2bf(v.w) };
    reinterpret_cast<ushort4*>(outp)[j] = o;
}

// ---------------- LayerNorm -> bf16 ----------------
__global__ __launch_bounds__(256) void ln_kernel(
    const float* __restrict__ x,
    const float* __restrict__ w,
    const float* __restrict__ bias,
    unsigned short* __restrict__ xn)
{
    int m = blockIdx.x, tid = threadIdx.x;
    const float4* xr = reinterpret_cast<const float4*>(x) + (size_t)m * 256;
    float4 r = xr[tid];
    float f0 = r.x, f1 = r.y, f2 = r.z, f3 = r.w;
    float s  = f0 + f1 + f2 + f3;
    float s2 = f0*f0 + f1*f1 + f2*f2 + f3*f3;
    #pragma unroll
    for (int off = 32; off > 0; off >>= 1) {
        s  += __shfl_down(s, off);
        s2 += __shfl_down(s2, off);
    }
    __shared__ float red[8];
    if ((tid & 63) == 0) { red[tid >> 6] = s; red[4 + (tid >> 6)] = s2; }
    __syncthreads();
    float st = red[0] + red[1] + red[2] + red[3];
    float qt = red[4] + red[5] + red[6] + red[7];
    float mu   = st * (1.f / 1024.f);
    float var  = qt * (1.f / 1024.f) - mu * mu;
    float rstd = rsqrtf(var + 1e-5f);
    float4 wv = reinterpret_cast<const float4*>(w)[tid];
    float4 bv = reinterpret_cast<const float4*>(bias)[tid];
    ushort4 o = { f2bf((f0 - mu) * rstd * wv.x + bv.x),
                  f2bf((f1 - mu) * rstd * wv.y + bv.y),
                  f2bf((f2 - mu) * rstd * wv.z + bv.z),
                  f2bf((f3 - mu) * rstd * wv.w + bv.w) };
    reinterpret_cast<ushort4*>(xn + (size_t)m * 1024)[tid] = o;
}

// ---------------- bf16 MFMA GEMM-NT, 128x64 tile, dbuf single-barrier K-loop -------
// 256 threads = 4 waves in 2x2; each wave 64x32 out. Per iter: 1 barrier,
// async-stage next tile into buf^1, compute current from buf.
__global__ __launch_bounds__(256) void gemm_bf16_nt(
    const unsigned short* __restrict__ A, int lda,
    const unsigned short* __restrict__ B, int ldb,
    int Kslice,
    float* __restrict__ C, int ldc,
    const float* __restrict__ bias,
    const float* __restrict__ resid,
    int ep, size_t Cstride)
{
    __shared__ short As[2 * 128 * 32];   // 16 KB
    __shared__ short Bs[2 * 64 * 32];    //  8 KB
    int tid = threadIdx.x;
    int z = blockIdx.z;
    A += (size_t)z * Kslice;
    B += (size_t)z * Kslice;
    C += (size_t)z * Cstride;
    int m0 = blockIdx.y * 128, n0 = blockIdx.x * 64;
    int lane = tid & 63, wave = tid >> 6;
    int wm = (wave >> 1) * 64, wn = (wave & 1) * 32;
    int frow = lane & 15, fq = lane >> 4;

    f32x4 acc[4][2] = {};

    // staging lane mapping: 16 rows per instr, lane>>2 = row, (lane&3)*8 = col
    int lrow = lane >> 2;
    int scol = (lane & 3) * 8;
    const unsigned short* AgL = A + (size_t)(m0 + wave * 32 + lrow) * lda + scol;
    const unsigned short* BgL = B + (size_t)(n0 + wave * 16 + lrow) * ldb + scol;
    int aoff = (wave * 32) * 32;
    int boff = (wave * 16) * 32;

    // prologue: stage tile 0 into buffer 0
    gload_lds16(AgL,                      As + aoff);
    gload_lds16(AgL + (size_t)16 * lda,   As + aoff + 16 * 32);
    gload_lds16(BgL,                      Bs + boff);

    int cur = 0;
    for (int k0 = 0; k0 < Kslice; k0 += 32) {
        __syncthreads();   // drains vmcnt(0): tile k0 resident; prev-iter reads done
        int nk = k0 + 32;
        if (nk < Kslice) {
            int nxt = cur ^ 1;
            gload_lds16(AgL + nk,                     As + nxt * 4096 + aoff);
            gload_lds16(AgL + (size_t)16 * lda + nk,  As + nxt * 4096 + aoff + 16 * 32);
            gload_lds16(BgL + nk,                     Bs + nxt * 2048 + boff);
        }
        const short* Ac = As + cur * 4096;
        const short* Bc = Bs + cur * 2048;
        bf16x8 af[4], bfr[2];
        #pragma unroll
        for (int i = 0; i < 4; ++i)
            af[i] = *reinterpret_cast<const bf16x8*>(Ac + (wm + i * 16 + frow) * 32 + fq * 8);
        #pragma unroll
        for (int j = 0; j < 2; ++j)
            bfr[j] = *reinterpret_cast<const bf16x8*>(Bc + (wn + j * 16 + frow) * 32 + fq * 8);
        #pragma unroll
        for (int i = 0; i < 4; ++i)
            #pragma unroll
            for (int j = 0; j < 2; ++j)
                acc[i][j] = __builtin_amdgcn_mfma_f32_16x16x32_bf16(af[i], bfr[j], acc[i][j], 0, 0, 0);
        cur ^= 1;
    }

    int cn = lane & 15, rq = (lane >> 4) * 4;
    #pragma unroll
    for (int i = 0; i < 4; ++i) {
        #pragma unroll
        for (int j = 0; j < 2; ++j) {
            #pragma unroll
            for (int r = 0; r < 4; ++r) {
                int row = m0 + wm + i * 16 + rq + r;
                int col = n0 + wn + j * 16 + cn;
                float v = acc[i][j][r];
                if (ep == 0) {
                    C[(size_t)row * ldc + col] = v;
                } else if (ep == 1) {
                    v += bias[col];
                    v = (v > 20.f) ? v : log1pf(__expf(v));
                    C[(size_t)row * ldc + col] = v;
                } else {
                    v += resid[(size_t)row * ldc + col];
                    C[(size_t)row * ldc + col] = v;
                }
            }
        }
    }
}

// ---------------- out = x + sum_z part[z] ----------------
__global__ __launch_bounds__(256) void out_reduce(
    const float* __restrict__ part, const float* __restrict__ x,
    float* __restrict__ out)
{
    int i = blockIdx.x * 256 + threadIdx.x;
    float4 s = reinterpret_cast<const float4*>(x)[i];
    #pragma unroll
    for (int z = 0; z < 4; ++z) {
        float4 p = reinterpret_cast<const float4*>(part + (size_t)z * 2097152)[i];
        s.x += p.x; s.y += p.y; s.z += p.z; s.w += p.w;
    }
    reinterpret_cast<float4*>(out)[i] = s;
}

// ---------------- xproj split-K fp32 ----------------
__global__ __launch_bounds__(256) void xproj_splitk(
    const float* __restrict__ A,
    const float* __restrict__ B,
    float* __restrict__ part)
{
    __shared__ float As[16][68];
    __shared__ float Bs[16][100];
    int tid = threadIdx.x;
    int m0 = blockIdx.x * 64;
    int k0 = blockIdx.y * 128;
    int tx = tid & 15;
    int ty = tid >> 4;
    float acc[4][6] = {};
    int arow = tid >> 2, akg = (tid & 3) << 2;
    int brow1 = (256 + tid) >> 2, bkg1 = ((256 + tid) & 3) << 2;

    for (int ks = 0; ks < 128; ks += 16) {
        float4 av = *reinterpret_cast<const float4*>(A + (size_t)(m0 + arow) * 2048 + k0 + ks + akg);
        float4 bv0 = make_float4(0.f, 0.f, 0.f, 0.f), bv1 = bv0;
        if (arow < 96)  bv0 = *reinterpret_cast<const float4*>(B + (size_t)arow * 2048 + k0 + ks + akg);
        if (brow1 < 96) bv1 = *reinterpret_cast<const float4*>(B + (size_t)brow1 * 2048 + k0 + ks + bkg1);
        __syncthreads();
        As[akg + 0][arow] = av.x; As[akg + 1][arow] = av.y;
        As[akg + 2][arow] = av.z; As[akg + 3][arow] = av.w;
        if (arow < 96) {
            Bs[akg + 0][arow] = bv0.x; Bs[akg + 1][arow] = bv0.y;
            Bs[akg + 2][arow] = bv0.z; Bs[akg + 3][arow] = bv0.w;
        }
        if (brow1 < 96) {
            Bs[bkg1 + 0][brow1] = bv1.x; Bs[bkg1 + 1][brow1] = bv1.y;
            Bs[bkg1 + 2][brow1] = bv1.z; Bs[bkg1 + 3][brow1] = bv1.w;
        }
        __syncthreads();
        #pragma unroll
        for (int k = 0; k < 16; ++k) {
            float aa[4], bb[6];
            #pragma unroll
            for (int i = 0; i < 4; ++i) aa[i] = As[k][ty * 4 + i];
            #pragma unroll
            for (int j = 0; j < 6; ++j) bb[j] = Bs[k][tx * 6 + j];
            #pragma unroll
            for (int i = 0; i < 4; ++i)
                #pragma unroll
                for (int j = 0; j < 6; ++j)
                    acc[i][j] = fmaf(aa[i], bb[j], acc[i][j]);
        }
    }
    float* p = part + (size_t)blockIdx.y * 196608;
    #pragma unroll
    for (int i = 0; i < 4; ++i)
        #pragma unroll
        for (int j = 0; j < 6; ++j)
            p[(size_t)(m0 + ty * 4 + i) * 96 + tx * 6 + j] = acc[i][j];
}

// reduce 16 partials -> xdbl; also emit dt_r (cols<64) as bf16
__global__ __launch_bounds__(256) void xproj_reduce(
    const float* __restrict__ part, float* __restrict__ xdbl,
    unsigned short* __restrict__ dtr)
{
    int i = blockIdx.x * 256 + threadIdx.x;   // 196608
    float s = 0.f;
    #pragma unroll
    for (int sd = 0; sd < 16; ++sd) s += part[(size_t)sd * 196608 + i];
    xdbl[i] = s;
    int m = i / 96, col = i - m * 96;
    if (col < 64) dtr[(size_t)m * 64 + col] = f2bf(s);
}

// ---------------- Depthwise causal conv (width 4) + SiLU ----------------
__global__ __launch_bounds__(256) void conv_silu_kernel(
    const float* __restrict__ xz,
    const float* __restrict__ cw,
    const float* __restrict__ cb,
    float* __restrict__ u)
{
    int idx = blockIdx.x * 256 + threadIdx.x;
    int e = idx & 2047;
    int m = idx >> 11;
    int l = m & 1023;
    float acc = cb[e];
    #pragma unroll
    for (int k = 0; k < 4; ++k) {
        int ls = l - 3 + k;
        if (ls >= 0)
            acc += cw[e * 4 + k] * xz[(size_t)(m - 3 + k) * 4096 + e];
    }
    u[(size_t)m * 2048 + e] = siluf(acc);
}

// ---------------- Chunked selective scan: 4 states/lane, LC=32, depth-2 pipeline ----
// grid 2048 = (b:2) x (et:32) x (c:32); 256 threads = 64 channels x 4 ngroups.
// Prefetch of iteration l+1 is unconditional: the one-past-end row lands in the
// adjacent live ws region (dt->hpart, u->xdbl, xdbl->dt, xz->u) - always in-bounds.
__global__ __launch_bounds__(256) void scan_part1(
    const float* __restrict__ dt,
    const float* __restrict__ u,
    const float* __restrict__ xdbl,
    const float* __restrict__ a_log,
    float* __restrict__ hpart,
    float* __restrict__ Aprod)
{
    int tid = threadIdx.x;
    int ch = tid >> 2, ng = tid & 3;
    int bid = blockIdx.x;
    int c = bid & 31, et = (bid >> 5) & 31, b = bid >> 10;
    int e = et * 64 + ch;
    float4 al = *reinterpret_cast<const float4*>(a_log + e * 16 + ng * 4);
    float A0 = -__expf(al.x), A1 = -__expf(al.y), A2 = -__expf(al.z), A3 = -__expf(al.w);
    size_t rbase = (size_t)b * 1024 + c * LC;
    const float* dt_p = dt + rbase * 2048 + e;
    const float* u_p  = u  + rbase * 2048 + e;
    const float* b_p  = xdbl + rbase * 96 + 64 + ng * 4;
    float h0 = 0.f, h1 = 0.f, h2 = 0.f, h3 = 0.f;
    float P0 = 1.f, P1 = 1.f, P2 = 1.f, P3 = 1.f;
    float dt_c = dt_p[0];
    float u_c  = u_p[0];
    float4 B_c = *reinterpret_cast<const float4*>(b_p);
    #pragma unroll 4
    for (int l = 0; l < LC; ++l) {
        float dt_n = dt_p[(size_t)(l + 1) * 2048];
        float u_n  = u_p[(size_t)(l + 1) * 2048];
        float4 B_n = *reinterpret_cast<const float4*>(b_p + (size_t)(l + 1) * 96);
        float du = dt_c * u_c;
        float d0 = __expf(dt_c * A0), d1 = __expf(dt_c * A1);
        float d2 = __expf(dt_c * A2), d3 = __expf(dt_c * A3);
        h0 = fmaf(d0, h0, du * B_c.x); P0 *= d0;
        h1 = fmaf(d1, h1, du * B_c.y); P1 *= d1;
        h2 = fmaf(d2, h2, du * B_c.z); P2 *= d2;
        h3 = fmaf(d3, h3, du * B_c.w); P3 *= d3;
        dt_c = dt_n; u_c = u_n; B_c = B_n;
    }
    size_t oidx = (size_t)c * 65536 + ((size_t)b * 2048 + e) * 16 + ng * 4;
    *reinterpret_cast<float4*>(hpart + oidx) = make_float4(h0, h1, h2, h3);
    *reinterpret_cast<float4*>(Aprod + oidx) = make_float4(P0, P1, P2, P3);
}

__global__ __launch_bounds__(256) void scan_combine(
    const float* __restrict__ hpart,
    const float* __restrict__ Aprod,
    float* __restrict__ hinit)
{
    int t = (blockIdx.x * 256 + threadIdx.x) * 4;
    float4 h = make_float4(0.f, 0.f, 0.f, 0.f);
    #pragma unroll
    for (int c = 0; c < NCHUNK; ++c) {
        *reinterpret_cast<float4*>(hinit + (size_t)c * 65536 + t) = h;
        float4 P = *reinterpret_cast<const float4*>(Aprod + (size_t)c * 65536 + t);
        float4 hp = *reinterpret_cast<const float4*>(hpart + (size_t)c * 65536 + t);
        h.x = fmaf(P.x, h.x, hp.x);
        h.y = fmaf(P.y, h.y, hp.y);
        h.z = fmaf(P.z, h.z, hp.z);
        h.w = fmaf(P.w, h.w, hp.w);
    }
}

__global__ __launch_bounds__(256) void scan_part2(
    const float* __restrict__ dt,
    const float* __restrict__ u,
    const float* __restrict__ xdbl,
    const float* __restrict__ xz,
    const float* __restrict__ a_log,
    const float* __restrict__ d_skip,
    const float* __restrict__ hinit,
    unsigned short* __restrict__ y)
{
    int tid = threadIdx.x;
    int ch = tid >> 2, ng = tid & 3;
    int bid = blockIdx.x;
    int c = bid & 31, et = (bid >> 5) & 31, b = bid >> 10;
    int e = et * 64 + ch;
    float4 al = *reinterpret_cast<const float4*>(a_log + e * 16 + ng * 4);
    float A0 = -__expf(al.x), A1 = -__expf(al.y), A2 = -__expf(al.z), A3 = -__expf(al.w);
    float dsk = d_skip[e];
    size_t rbase = (size_t)b * 1024 + c * LC;
    const float* dt_p = dt + rbase * 2048 + e;
    const float* u_p  = u  + rbase * 2048 + e;
    const float* z_p  = xz + rbase * 4096 + 2048 + e;
    const float* bc_p = xdbl + rbase * 96 + 64 + ng * 4;
    unsigned short* y_p = y + rbase * 2048 + e;
    size_t oidx = (size_t)c * 65536 + ((size_t)b * 2048 + e) * 16 + ng * 4;
    float4 hi = *reinterpret_cast<const float4*>(hinit + oidx);
    float h0 = hi.x, h1 = hi.y, h2 = hi.z, h3 = hi.w;
    float dt_c = dt_p[0];
    float u_c  = u_p[0];
    float4 B_c = *reinterpret_cast<const float4*>(bc_p);
    float4 C_c = *reinterpret_cast<const float4*>(bc_p + 16);
    #pragma unroll 4
    for (int l = 0; l < LC; ++l) {
        float dt_n = dt_p[(size_t)(l + 1) * 2048];
        float u_n  = u_p[(size_t)(l + 1) * 2048];
        float4 B_n = *reinterpret_cast<const float4*>(bc_p + (size_t)(l + 1) * 96);
        float4 C_n = *reinterpret_cast<const float4*>(bc_p + (size_t)(l + 1) * 96 + 16);
        float du = dt_c * u_c;
        float d0 = __expf(dt_c * A0), d1 = __expf(dt_c * A1);
        float d2 = __expf(dt_c * A2), d3 = __expf(dt_c * A3);
        h0 = fmaf(d0, h0, du * B_c.x);
        h1 = fmaf(d1, h1, du * B_c.y);
        h2 = fmaf(d2, h2, du * B_c.z);
        h3 = fmaf(d3, h3, du * B_c.w);
        float p = h0 * C_c.x + h1 * C_c.y + h2 * C_c.z + h3 * C_c.w;
        p += __shfl_xor(p, 1);
        p += __shfl_xor(p, 2);
        if (ng == 0) {
            float zv = z_p[(size_t)l * 4096];
            y_p[(size_t)l * 2048] = f2bf((p + u_c * dsk) * siluf(zv));
        }
        dt_c = dt_n; u_c = u_n; B_c = B_n; C_c = C_n;
    }
}

extern "C" void kernel_launch(void* const* d_in, const int* in_sizes, int n_in,
                              void* d_out, int out_size, void* d_ws, size_t ws_size,
                              hipStream_t stream) {
    const float* x       = (const float*)d_in[0];
    const float* ln_w    = (const float*)d_in[1];
    const float* ln_b    = (const float*)d_in[2];
    const float* w_in    = (const float*)d_in[3];
    const float* conv_w  = (const float*)d_in[4];
    const float* conv_b  = (const float*)d_in[5];
    const float* w_xproj = (const float*)d_in[6];
    const float* w_dt    = (const float*)d_in[7];
    const float* b_dt    = (const float*)d_in[8];
    const float* a_log   = (const float*)d_in[9];
    const float* d_skip  = (const float*)d_in[10];
    const float* w_out   = (const float*)d_in[11];
    float* out = (float*)d_out;

    float* ws = (float*)d_ws;
    unsigned short* xn_b    = (unsigned short*)(ws);
    float* xz    = ws + 1048576;
    float* u     = ws + 9437184;
    float* xdbl  = ws + 13631488;
    float* dt    = ws + 13828096;
    float* hpart = ws + 18022400;   // 2M
    float* Aprod = ws + 20119552;   // 2M (spills into dead w_in_b)
    float* hinit = ws + 22216704;   // 2M
    float* xpart = ws + 18022400;   // xproj partials (pre-scan alias)
    float* opart = xz;              // out-proj partials (xz dead after part2)
    unsigned short* y_b     = (unsigned short*)(ws + 18022400); // post-combine alias
    unsigned short* w_in_b  = (unsigned short*)(ws + 21168128);
    unsigned short* w_dt_b  = (unsigned short*)(ws + 24313856);
    unsigned short* dtr_b   = (unsigned short*)(ws + 24379392);
    unsigned short* w_out_b = (unsigned short*)(ws + 24444928); // past scan scratch, no alias

    // 0. all weight converts in one launch
    f2b_all<<<6272, 256, 0, stream>>>(w_in, w_in_b, w_out, w_out_b, w_dt, w_dt_b);
    // 1. LayerNorm -> bf16
    ln_kernel<<<2048, 256, 0, stream>>>(x, ln_w, ln_b, xn_b);
    // 2. xz = xn @ w_in^T   (2048 x 4096 x 1024)  MFMA, 128x64 tiles -> 1024 blocks
    gemm_bf16_nt<<<dim3(64, 16, 1), 256, 0, stream>>>(xn_b, 1024, w_in_b, 1024, 1024,
                                                      xz, 4096, nullptr, nullptr, 0, 0);
    // 3. depthwise conv + silu -> u
    conv_silu_kernel<<<16384, 256, 0, stream>>>(xz, conv_w, conv_b, u);
    // 4. x_dbl = u @ w_xproj^T  (2048 x 96 x 2048)  fp32 split-K; reduce also emits dt_r bf16
    xproj_splitk<<<dim3(32, 16), 256, 0, stream>>>(u, w_xproj, xpart);
    xproj_reduce<<<768, 256, 0, stream>>>(xpart, xdbl, dtr_b);
    // 5. dt = softplus(dt_r @ w_dt^T + b_dt)  MFMA -> 512 blocks
    gemm_bf16_nt<<<dim3(32, 16, 1), 256, 0, stream>>>(dtr_b, 64, w_dt_b, 64, 64,
                                                      dt, 2048, b_dt, nullptr, 1, 0);
    // 6. chunked selective scan (LC=32, 32 chunks) -> y (bf16)
    scan_part1<<<2048, 256, 0, stream>>>(dt, u, xdbl, a_log, hpart, Aprod);
    scan_combine<<<64, 256, 0, stream>>>(hpart, Aprod, hinit);
    scan_part2<<<2048, 256, 0, stream>>>(dt, u, xdbl, xz, a_log, d_skip, hinit, y_b);
    // 7. out-proj split-K x4 (128x64 tiles -> 1024 blocks) + reduce(+residual)
    gemm_bf16_nt<<<dim3(16, 16, 4), 256, 0, stream>>>(y_b, 2048, w_out_b, 2048, 512,
                                                      opart, 1024, nullptr, nullptr, 0, 2097152);
    out_reduce<<<2048, 256, 0, stream>>>(opart, x, out);
}